// Round 1
// baseline (656.448 us; speedup 1.0000x reference)
//
#include <hip/hip_runtime.h>

// TypeAwareEdgeUpdate: out = relu(relu(cat[n1@W1[t1]+b1, n2@W2[t2]+b2, e@We+be]) @ Wout + bout)
// Strategy: counting-sort rows by (t1,t2) pair -> 64-row tiles share both weight
// matrices -> fused bf16 MFMA kernel (5.25 GEMMs per tile), fp32 accumulate.

#define J_TYPES 17
#define PAIRS   (J_TYPES * J_TYPES)
#define DN      256
#define DE      128
#define DO      256
#define TILE    64

typedef short bf16x8 __attribute__((ext_vector_type(8)));
typedef float f32x4  __attribute__((ext_vector_type(4)));

__device__ __forceinline__ unsigned short f2bf(float x) {
  unsigned u = __float_as_uint(x);
  return (unsigned short)((u + 0x7fffu + ((u >> 16) & 1u)) >> 16);  // RNE
}

// ---------------- weight prep: bf16 + transpose to [out][in] ----------------
__global__ void prep_w_k(const float* __restrict__ W1, const float* __restrict__ W2,
                         const float* __restrict__ We, const float* __restrict__ Wout,
                         unsigned short* __restrict__ W1t, unsigned short* __restrict__ W2t,
                         unsigned short* __restrict__ Wet, unsigned short* __restrict__ Ut) {
  const int SZW = J_TYPES * 65536;
  const int total = SZW * 2 + DE * DO + 3 * 65536;
  for (int i = blockIdx.x * blockDim.x + threadIdx.x; i < total;
       i += gridDim.x * blockDim.x) {
    int idx = i;
    if (idx < SZW) {                       // W1t[j][n][k] = W1[j][k][n]
      int j = idx >> 16, r = idx & 65535, n = r >> 8, k = r & 255;
      W1t[idx] = f2bf(W1[(size_t)(j * 256 + k) * 256 + n]);
    } else if ((idx -= SZW) < SZW) {       // W2t
      int j = idx >> 16, r = idx & 65535, n = r >> 8, k = r & 255;
      W2t[idx] = f2bf(W2[(size_t)(j * 256 + k) * 256 + n]);
    } else if ((idx -= SZW) < DE * DO) {   // Wet[n][k] = We[k][n]
      int n = idx >> 7, k = idx & 127;
      Wet[idx] = f2bf(We[k * 256 + n]);
    } else {                               // Ut[p][n][k] = Wout[p*256+k][n]
      idx -= DE * DO;
      int p = idx >> 16, r = idx & 65535, n = r >> 8, k = r & 255;
      Ut[idx] = f2bf(Wout[(size_t)(p * 256 + k) * 256 + n]);
    }
  }
}

// ---------------- counting sort by pair ----------------
__global__ void hist_k(const int* __restrict__ ty1, const int* __restrict__ ty2,
                       int* __restrict__ cnt, int N) {
  __shared__ int h[PAIRS];
  for (int i = threadIdx.x; i < PAIRS; i += blockDim.x) h[i] = 0;
  __syncthreads();
  for (int i = blockIdx.x * blockDim.x + threadIdx.x; i < N;
       i += gridDim.x * blockDim.x)
    atomicAdd(&h[ty1[i] * J_TYPES + ty2[i]], 1);
  __syncthreads();
  for (int i = threadIdx.x; i < PAIRS; i += blockDim.x) {
    int v = h[i];
    if (v) atomicAdd(&cnt[i], v);
  }
}

__global__ void scan_tiles_k(const int* __restrict__ cnt, int* __restrict__ seg,
                             int* __restrict__ tpair, int* __restrict__ tstart,
                             int* __restrict__ tnr, int* __restrict__ ntl) {
  __shared__ int s1[512], s2[512];
  int t = threadIdx.x;                               // 512 threads
  int c  = (t < PAIRS) ? cnt[t] : 0;
  int nt = (c + TILE - 1) / TILE;
  s1[t] = c; s2[t] = nt;
  __syncthreads();
  for (int o = 1; o < 512; o <<= 1) {                // Hillis-Steele inclusive
    int v1 = (t >= o) ? s1[t - o] : 0;
    int v2 = (t >= o) ? s2[t - o] : 0;
    __syncthreads();
    s1[t] += v1; s2[t] += v2;
    __syncthreads();
  }
  if (t < PAIRS) {
    int segstart = s1[t] - c;
    int tbase    = s2[t] - nt;
    seg[t] = segstart;
    for (int i = 0; i < nt; ++i) {
      tpair[tbase + i]  = t;
      tstart[tbase + i] = segstart + i * TILE;
      int rem = c - i * TILE;
      tnr[tbase + i] = rem < TILE ? rem : TILE;
    }
  }
  if (t == 511) ntl[0] = s2[511];
}

__global__ void scatter_k(const int* __restrict__ ty1, const int* __restrict__ ty2,
                          const int* __restrict__ seg, int* __restrict__ c2,
                          int* __restrict__ ridx, int N) {
  for (int i = blockIdx.x * blockDim.x + threadIdx.x; i < N;
       i += gridDim.x * blockDim.x) {
    int p = ty1[i] * J_TYPES + ty2[i];
    int pos = seg[p] + atomicAdd(&c2[p], 1);
    ridx[pos] = i;
  }
}

// ---------------- fused tile kernel ----------------
// 4 waves/block; wave w owns output cols [w*64, w*64+64), all 64 rows.
// A-frag: lane l -> row (l&15), k = (l>>4)*8 .. +7 (16B contiguous, LDS)
// B-frag: lane l -> col (l&15), k contiguous (16B from transposed weights, L2)
// D-frag: lane l -> col (l&15), row = (l>>4)*4 + reg   [guide-verified m89/m91]

template <int K>
__device__ __forceinline__ void stage_tile(const float* __restrict__ src,
                                           const int* srow, unsigned short* lds,
                                           int ld) {
  const int K4 = K / 4;
  for (int i = threadIdx.x; i < TILE * K4; i += 256) {
    int r = i / K4, c4 = (i - r * K4) * 4;
    float4 v = make_float4(0.f, 0.f, 0.f, 0.f);
    int sr = srow[r];
    if (sr >= 0) v = *reinterpret_cast<const float4*>(src + (size_t)sr * K + c4);
    unsigned lo = (unsigned)f2bf(v.x) | ((unsigned)f2bf(v.y) << 16);
    unsigned hi = (unsigned)f2bf(v.z) | ((unsigned)f2bf(v.w) << 16);
    *reinterpret_cast<uint2*>(lds + r * ld + c4) = make_uint2(lo, hi);
  }
}

template <int K>
__device__ __forceinline__ void gemm_acc(const unsigned short* lds, int ld,
                                         const unsigned short* __restrict__ Wt,
                                         f32x4 acc[4][4], int r0, int kg, int wcol0) {
#pragma unroll 2
  for (int kk = 0; kk < K; kk += 32) {
    bf16x8 af[4], bf[4];
#pragma unroll
    for (int rs = 0; rs < 4; ++rs)
      af[rs] = *reinterpret_cast<const bf16x8*>(lds + (rs * 16 + r0) * ld + kk + kg);
#pragma unroll
    for (int cs = 0; cs < 4; ++cs)
      bf[cs] = *reinterpret_cast<const bf16x8*>(
          Wt + (size_t)(wcol0 + cs * 16 + r0) * K + kk + kg);
#pragma unroll
    for (int rs = 0; rs < 4; ++rs)
#pragma unroll
      for (int cs = 0; cs < 4; ++cs)
        acc[rs][cs] = __builtin_amdgcn_mfma_f32_16x16x32_bf16(af[rs], bf[cs],
                                                              acc[rs][cs], 0, 0, 0);
  }
}

__device__ __forceinline__ void epi_inter(f32x4 acc[4][4], const float* __restrict__ bias,
                                          unsigned short* ldsT, int r0, int rb,
                                          int wcol0) {
#pragma unroll
  for (int cs = 0; cs < 4; ++cs) {
    int col = wcol0 + cs * 16 + r0;
    float b = bias[col];
#pragma unroll
    for (int rs = 0; rs < 4; ++rs)
#pragma unroll
      for (int i = 0; i < 4; ++i) {
        float v = fmaxf(acc[rs][cs][i] + b, 0.f);
        ldsT[(rs * 16 + rb + i) * 264 + col] = f2bf(v);
      }
  }
}

__global__ __launch_bounds__(256, 2) void fused_k(
    const float* __restrict__ n1, const float* __restrict__ n2,
    const float* __restrict__ eg, const unsigned short* __restrict__ W1t,
    const unsigned short* __restrict__ W2t, const unsigned short* __restrict__ Wet,
    const unsigned short* __restrict__ Ut, const float* __restrict__ b1,
    const float* __restrict__ b2, const float* __restrict__ be,
    const float* __restrict__ bout, const int* __restrict__ ridx,
    const int* __restrict__ tpair, const int* __restrict__ tstart,
    const int* __restrict__ tnr, const int* __restrict__ ntl,
    float* __restrict__ out) {
  if ((int)blockIdx.x >= ntl[0]) return;
  const int pr = tpair[blockIdx.x];
  const int t1 = pr / J_TYPES, t2 = pr % J_TYPES;
  const int ts = tstart[blockIdx.x];
  const int nrows = tnr[blockIdx.x];

  __shared__ unsigned short ldsA[TILE * 264];
  __shared__ unsigned short ldsT[TILE * 264];
  __shared__ int srow[TILE];

  const int lane = threadIdx.x & 63;
  const int wave = threadIdx.x >> 6;
  const int wcol0 = wave * 64;
  const int r0 = lane & 15;
  const int kg = (lane >> 4) * 8;
  const int rb = (lane >> 4) * 4;

  if (threadIdx.x < TILE)
    srow[threadIdx.x] = (threadIdx.x < nrows) ? ridx[ts + threadIdx.x] : -1;
  __syncthreads();

  const f32x4 vzero = {0.f, 0.f, 0.f, 0.f};
  f32x4 accO[4][4], accT[4][4];
#pragma unroll
  for (int a = 0; a < 4; ++a)
#pragma unroll
    for (int b = 0; b < 4; ++b) accO[a][b] = vzero;

  // ---- path 1: relu(n1@W1[t1]+b1) @ U0
  stage_tile<DN>(n1, srow, ldsA, 264);
  __syncthreads();
#pragma unroll
  for (int a = 0; a < 4; ++a)
#pragma unroll
    for (int b = 0; b < 4; ++b) accT[a][b] = vzero;
  gemm_acc<DN>(ldsA, 264, W1t + (size_t)t1 * 65536, accT, r0, kg, wcol0);
  epi_inter(accT, b1 + t1 * 256, ldsT, r0, rb, wcol0);
  __syncthreads();
  gemm_acc<DO>(ldsT, 264, Ut, accO, r0, kg, wcol0);
  stage_tile<DN>(n2, srow, ldsA, 264);  // safe: all waves past G1 (sync above)
  __syncthreads();

  // ---- path 2: relu(n2@W2[t2]+b2) @ U1
#pragma unroll
  for (int a = 0; a < 4; ++a)
#pragma unroll
    for (int b = 0; b < 4; ++b) accT[a][b] = vzero;
  gemm_acc<DN>(ldsA, 264, W2t + (size_t)t2 * 65536, accT, r0, kg, wcol0);
  epi_inter(accT, b2 + t2 * 256, ldsT, r0, rb, wcol0);
  __syncthreads();
  gemm_acc<DO>(ldsT, 264, Ut + 65536, accO, r0, kg, wcol0);
  stage_tile<DE>(eg, srow, ldsA, 136);
  __syncthreads();

  // ---- path 3: relu(e@We+be) @ U2
#pragma unroll
  for (int a = 0; a < 4; ++a)
#pragma unroll
    for (int b = 0; b < 4; ++b) accT[a][b] = vzero;
  gemm_acc<DE>(ldsA, 136, Wet, accT, r0, kg, wcol0);
  epi_inter(accT, be, ldsT, r0, rb, wcol0);
  __syncthreads();
  gemm_acc<DO>(ldsT, 264, Ut + 2 * 65536, accO, r0, kg, wcol0);

  // ---- epilogue: relu(accO + bout) -> scattered rows
#pragma unroll
  for (int cs = 0; cs < 4; ++cs) {
    int col = wcol0 + cs * 16 + r0;
    float bo = bout[col];
#pragma unroll
    for (int rs = 0; rs < 4; ++rs)
#pragma unroll
      for (int i = 0; i < 4; ++i) {
        int row = rs * 16 + rb + i;
        if (row < nrows) {
          float v = fmaxf(accO[rs][cs][i] + bo, 0.f);
          out[(size_t)srow[row] * 256 + col] = v;
        }
      }
  }
}

// ---------------- launcher ----------------
extern "C" void kernel_launch(void* const* d_in, const int* in_sizes, int n_in,
                              void* d_out, int out_size, void* d_ws, size_t ws_size,
                              hipStream_t stream) {
  const float* n1   = (const float*)d_in[0];
  const float* n2   = (const float*)d_in[1];
  const float* eg   = (const float*)d_in[2];
  const int*   ty1  = (const int*)d_in[3];
  const int*   ty2  = (const int*)d_in[4];
  const float* W1   = (const float*)d_in[5];
  const float* b1   = (const float*)d_in[6];
  const float* W2   = (const float*)d_in[7];
  const float* b2   = (const float*)d_in[8];
  const float* We   = (const float*)d_in[9];
  const float* be   = (const float*)d_in[10];
  const float* Wout = (const float*)d_in[11];
  const float* bout = (const float*)d_in[12];
  float* out = (float*)d_out;

  const int N = in_sizes[0] / DN;
  const int maxt = (N + TILE - 1) / TILE + PAIRS;

  char* ws = (char*)d_ws;
  size_t off = 0;
  auto take = [&](size_t bytes) -> char* {
    char* p = ws + off;
    off += (bytes + 255) & ~(size_t)255;
    return p;
  };
  int* cnt = (int*)take(PAIRS * 4);
  int* c2  = (int*)take(PAIRS * 4);
  int* ntl = (int*)take(4);
  int* seg = (int*)take((PAIRS + 1) * 4);
  int* tp  = (int*)take((size_t)maxt * 4);
  int* tst = (int*)take((size_t)maxt * 4);
  int* tnr = (int*)take((size_t)maxt * 4);
  int* ridx = (int*)take((size_t)N * 4);
  unsigned short* W1t = (unsigned short*)take((size_t)J_TYPES * 65536 * 2);
  unsigned short* W2t = (unsigned short*)take((size_t)J_TYPES * 65536 * 2);
  unsigned short* Wet = (unsigned short*)take((size_t)DE * DO * 2);
  unsigned short* Ut  = (unsigned short*)take((size_t)3 * 65536 * 2);
  (void)ws_size; (void)n_in; (void)out_size;

  // zero cnt/c2/ntl (contiguous prefix region)
  hipMemsetAsync(cnt, 0, (size_t)((char*)seg - (char*)cnt), stream);
  prep_w_k<<<1024, 256, 0, stream>>>(W1, W2, We, Wout, W1t, W2t, Wet, Ut);
  hist_k<<<400, 256, 0, stream>>>(ty1, ty2, cnt, N);
  scan_tiles_k<<<1, 512, 0, stream>>>(cnt, seg, tp, tst, tnr, ntl);
  scatter_k<<<400, 256, 0, stream>>>(ty1, ty2, seg, c2, ridx, N);
  fused_k<<<maxt, 256, 0, stream>>>(n1, n2, eg, W1t, W2t, Wet, Ut, b1, b2, be, bout,
                                    ridx, tp, tst, tnr, ntl, out);
}

// Round 2
// 537.016 us; speedup vs baseline: 1.2224x; 1.2224x over previous
//
#include <hip/hip_runtime.h>

// TypeAwareEdgeUpdate: out = relu(relu(cat[n1@W1[t1]+b1, n2@W2[t2]+b2, e@We+be]) @ Wout + bout)
// Counting-sort rows by (t1,t2) -> 64-row tiles share weights -> fused bf16 MFMA.
// R2: single-ldsA + half ldsT (51KB, 3 blk/CU), accT=32 regs (3 waves/SIMD),
//     cvt_pk_bf16 packing, XCD swizzle, block-aggregated scatter.

#define J_TYPES 17
#define PAIRS   (J_TYPES * J_TYPES)
#define DN      256
#define DE      128
#define DO      256
#define TILE    64
#define LDA     264   // ldsA stride (shorts) for K=256
#define LDE     136   // ldsA stride for K=128 (edge path)
#define LDT     136   // ldsT stride (128 cols + pad)

typedef short bf16x8 __attribute__((ext_vector_type(8)));
typedef float f32x4  __attribute__((ext_vector_type(4)));

__device__ __forceinline__ unsigned short f2bf(float x) {
  unsigned u = __float_as_uint(x);
  return (unsigned short)((u + 0x7fffu + ((u >> 16) & 1u)) >> 16);  // RNE
}

__device__ __forceinline__ unsigned cvtpk(float lo, float hi) {
  unsigned r;
  asm("v_cvt_pk_bf16_f32 %0, %1, %2" : "=v"(r) : "v"(lo), "v"(hi));
  return r;  // lo16 = bf16(lo), hi16 = bf16(hi), RNE
}

// ---------------- weight prep: bf16 + transpose to [out][in] ----------------
__global__ void prep_w_k(const float* __restrict__ W1, const float* __restrict__ W2,
                         const float* __restrict__ We, const float* __restrict__ Wout,
                         unsigned short* __restrict__ W1t, unsigned short* __restrict__ W2t,
                         unsigned short* __restrict__ Wet, unsigned short* __restrict__ Ut) {
  const int SZW = J_TYPES * 65536;
  const int total = SZW * 2 + DE * DO + 3 * 65536;
  for (int i = blockIdx.x * blockDim.x + threadIdx.x; i < total;
       i += gridDim.x * blockDim.x) {
    int idx = i;
    if (idx < SZW) {                       // W1t[j][n][k] = W1[j][k][n]
      int j = idx >> 16, r = idx & 65535, n = r >> 8, k = r & 255;
      W1t[idx] = f2bf(W1[(size_t)(j * 256 + k) * 256 + n]);
    } else if ((idx -= SZW) < SZW) {       // W2t
      int j = idx >> 16, r = idx & 65535, n = r >> 8, k = r & 255;
      W2t[idx] = f2bf(W2[(size_t)(j * 256 + k) * 256 + n]);
    } else if ((idx -= SZW) < DE * DO) {   // Wet[n][k] = We[k][n]
      int n = idx >> 7, k = idx & 127;
      Wet[idx] = f2bf(We[k * 256 + n]);
    } else {                               // Ut[p][n][k] = Wout[p*256+k][n]
      idx -= DE * DO;
      int p = idx >> 16, r = idx & 65535, n = r >> 8, k = r & 255;
      Ut[idx] = f2bf(Wout[(size_t)(p * 256 + k) * 256 + n]);
    }
  }
}

// ---------------- counting sort by pair ----------------
__global__ void hist_k(const int* __restrict__ ty1, const int* __restrict__ ty2,
                       int* __restrict__ cnt, int N) {
  __shared__ int h[PAIRS];
  for (int i = threadIdx.x; i < PAIRS; i += blockDim.x) h[i] = 0;
  __syncthreads();
  for (int i = blockIdx.x * blockDim.x + threadIdx.x; i < N;
       i += gridDim.x * blockDim.x)
    atomicAdd(&h[ty1[i] * J_TYPES + ty2[i]], 1);
  __syncthreads();
  for (int i = threadIdx.x; i < PAIRS; i += blockDim.x) {
    int v = h[i];
    if (v) atomicAdd(&cnt[i], v);
  }
}

__global__ void scan_tiles_k(const int* __restrict__ cnt, int* __restrict__ seg,
                             int* __restrict__ tpair, int* __restrict__ tstart,
                             int* __restrict__ tnr, int* __restrict__ ntl) {
  __shared__ int s1[512], s2[512];
  int t = threadIdx.x;                               // 512 threads
  int c  = (t < PAIRS) ? cnt[t] : 0;
  int nt = (c + TILE - 1) / TILE;
  s1[t] = c; s2[t] = nt;
  __syncthreads();
  for (int o = 1; o < 512; o <<= 1) {                // Hillis-Steele inclusive
    int v1 = (t >= o) ? s1[t - o] : 0;
    int v2 = (t >= o) ? s2[t - o] : 0;
    __syncthreads();
    s1[t] += v1; s2[t] += v2;
    __syncthreads();
  }
  if (t < PAIRS) {
    int segstart = s1[t] - c;
    int tbase    = s2[t] - nt;
    seg[t] = segstart;
    for (int i = 0; i < nt; ++i) {
      tpair[tbase + i]  = t;
      tstart[tbase + i] = segstart + i * TILE;
      int rem = c - i * TILE;
      tnr[tbase + i] = rem < TILE ? rem : TILE;
    }
  }
  if (t == 511) ntl[0] = s2[511];
}

// block-aggregated scatter: one global atomic per (block,pair)
__global__ void scatter_k(const int* __restrict__ ty1, const int* __restrict__ ty2,
                          const int* __restrict__ seg, int* __restrict__ c2,
                          int* __restrict__ ridx, int N) {
  __shared__ int lh[PAIRS], lb[PAIRS];
  int chunk = (N + gridDim.x - 1) / gridDim.x;
  int lo = blockIdx.x * chunk;
  int hi = lo + chunk; if (hi > N) hi = N;
  for (int i = threadIdx.x; i < PAIRS; i += blockDim.x) lh[i] = 0;
  __syncthreads();
  for (int i = lo + threadIdx.x; i < hi; i += blockDim.x)
    atomicAdd(&lh[ty1[i] * J_TYPES + ty2[i]], 1);
  __syncthreads();
  for (int i = threadIdx.x; i < PAIRS; i += blockDim.x) {
    int v = lh[i];
    lb[i] = v ? atomicAdd(&c2[i], v) : 0;
    lh[i] = 0;
  }
  __syncthreads();
  for (int i = lo + threadIdx.x; i < hi; i += blockDim.x) {
    int p = ty1[i] * J_TYPES + ty2[i];
    int pos = seg[p] + lb[p] + atomicAdd(&lh[p], 1);
    ridx[pos] = i;
  }
}

// ---------------- fused tile kernel ----------------
// 4 waves/block. tmp (intermediate) computed in two 128-col halves:
//   gemm1: wave w computes tmp[64][h*128 + w*32 .. +32)   (accT = 8 frags = 32 regs)
//   gemm2: wave w computes accO[64][w*64 .. +64) over k-half (accO = 16 frags)
// A-frag: lane l -> row (l&15), k = (l>>4)*8..+7 ; B-frag: col (l&15), k contig
// D-frag: col = l&15, row = (l>>4)*4 + reg

template <int K, int LD>
__device__ __forceinline__ void stage_tile(const float* __restrict__ src,
                                           const int* srow, unsigned short* lds) {
  constexpr int K4 = K / 4;
  for (int i = threadIdx.x; i < TILE * K4; i += 256) {
    int r = i / K4, c4 = (i - r * K4) * 4;
    int sr = srow[r];
    float4 v = make_float4(0.f, 0.f, 0.f, 0.f);
    if (sr >= 0) v = *reinterpret_cast<const float4*>(src + (size_t)sr * K + c4);
    unsigned lo = cvtpk(v.x, v.y), hi = cvtpk(v.z, v.w);
    *reinterpret_cast<uint2*>(lds + r * LD + c4) = make_uint2(lo, hi);
  }
}

template <int K, int LD>
__device__ __forceinline__ void gemm1(const unsigned short* ldsA,
                                      const unsigned short* __restrict__ Wp,
                                      f32x4 accT[4][2], int r0, int kg, int colbase) {
#pragma unroll 2
  for (int kk = 0; kk < K; kk += 32) {
    bf16x8 af[4], bf[2];
#pragma unroll
    for (int rs = 0; rs < 4; ++rs)
      af[rs] = *reinterpret_cast<const bf16x8*>(ldsA + (rs * 16 + r0) * LD + kk + kg);
#pragma unroll
    for (int cs = 0; cs < 2; ++cs)
      bf[cs] = *reinterpret_cast<const bf16x8*>(
          Wp + (size_t)(colbase + cs * 16) * K + kk + kg);
#pragma unroll
    for (int rs = 0; rs < 4; ++rs)
#pragma unroll
      for (int cs = 0; cs < 2; ++cs)
        accT[rs][cs] = __builtin_amdgcn_mfma_f32_16x16x32_bf16(af[rs], bf[cs],
                                                               accT[rs][cs], 0, 0, 0);
  }
}

__device__ __forceinline__ void epi_half(f32x4 accT[4][2], const float* __restrict__ bias,
                                         unsigned short* ldsT, int r0, int rb,
                                         int wave, int h) {
#pragma unroll
  for (int cs = 0; cs < 2; ++cs) {
    int col_l = wave * 32 + cs * 16 + r0;
    float b = bias[h * 128 + col_l];
#pragma unroll
    for (int rs = 0; rs < 4; ++rs) {
      float x0 = fmaxf(accT[rs][cs][0] + b, 0.f);
      float x1 = fmaxf(accT[rs][cs][1] + b, 0.f);
      float x2 = fmaxf(accT[rs][cs][2] + b, 0.f);
      float x3 = fmaxf(accT[rs][cs][3] + b, 0.f);
      unsigned w01 = cvtpk(x0, x1), w23 = cvtpk(x2, x3);
      int row = rs * 16 + rb;
      ldsT[(row + 0) * LDT + col_l] = (unsigned short)w01;
      ldsT[(row + 1) * LDT + col_l] = (unsigned short)(w01 >> 16);
      ldsT[(row + 2) * LDT + col_l] = (unsigned short)w23;
      ldsT[(row + 3) * LDT + col_l] = (unsigned short)(w23 >> 16);
    }
  }
}

__device__ __forceinline__ void gemm2(const unsigned short* ldsT,
                                      const unsigned short* __restrict__ Up,
                                      f32x4 accO[4][4], int r0, int kg, int wcol0,
                                      int h) {
#pragma unroll 2
  for (int kk = 0; kk < 128; kk += 32) {
    bf16x8 af[4], bf[4];
#pragma unroll
    for (int rs = 0; rs < 4; ++rs)
      af[rs] = *reinterpret_cast<const bf16x8*>(ldsT + (rs * 16 + r0) * LDT + kk + kg);
#pragma unroll
    for (int cs = 0; cs < 4; ++cs)
      bf[cs] = *reinterpret_cast<const bf16x8*>(
          Up + (size_t)(wcol0 + cs * 16 + r0) * 256 + h * 128 + kk + kg);
#pragma unroll
    for (int rs = 0; rs < 4; ++rs)
#pragma unroll
      for (int cs = 0; cs < 4; ++cs)
        accO[rs][cs] = __builtin_amdgcn_mfma_f32_16x16x32_bf16(af[rs], bf[cs],
                                                               accO[rs][cs], 0, 0, 0);
  }
}

template <int K, int LD>
__device__ __forceinline__ void do_path(const float* __restrict__ X,
                                        const unsigned short* __restrict__ Wp,
                                        const float* __restrict__ bias,
                                        const unsigned short* __restrict__ Up,
                                        const int* srow, unsigned short* ldsA,
                                        unsigned short* ldsT, f32x4 accO[4][4],
                                        int r0, int kg, int rb, int wave, int wcol0) {
  stage_tile<K, LD>(X, srow, ldsA);
  __syncthreads();
#pragma unroll
  for (int h = 0; h < 2; ++h) {
    f32x4 accT[4][2];
    const f32x4 vz = {0.f, 0.f, 0.f, 0.f};
#pragma unroll
    for (int a = 0; a < 4; ++a) { accT[a][0] = vz; accT[a][1] = vz; }
    gemm1<K, LD>(ldsA, Wp, accT, r0, kg, h * 128 + wave * 32 + r0);
    __syncthreads();   // prior ldsT readers (prev gemm2) done
    epi_half(accT, bias, ldsT, r0, rb, wave, h);
    __syncthreads();   // ldsT visible to all
    gemm2(ldsT, Up, accO, r0, kg, wcol0, h);
    // no barrier: next gemm1 reads only ldsA; next epi is barrier-protected
  }
}

__global__ __launch_bounds__(256, 3) void fused_k(
    const float* __restrict__ n1, const float* __restrict__ n2,
    const float* __restrict__ eg, const unsigned short* __restrict__ W1t,
    const unsigned short* __restrict__ W2t, const unsigned short* __restrict__ Wet,
    const unsigned short* __restrict__ Ut, const float* __restrict__ b1,
    const float* __restrict__ b2, const float* __restrict__ be,
    const float* __restrict__ bout, const int* __restrict__ ridx,
    const int* __restrict__ tpair, const int* __restrict__ tstart,
    const int* __restrict__ tnr, const int* __restrict__ ntl,
    float* __restrict__ out) {
  // bijective XCD swizzle: same-pair tiles (consecutive) -> same XCD's L2
  int nwg = gridDim.x, orig = blockIdx.x;
  int q = nwg >> 3, rr = nwg & 7, xc = orig & 7, sidx = orig >> 3;
  int tile = (xc < rr ? xc * (q + 1) : rr * (q + 1) + (xc - rr) * q) + sidx;
  if (tile >= ntl[0]) return;

  const int pr = tpair[tile];
  const int t1 = pr / J_TYPES, t2 = pr % J_TYPES;
  const int ts = tstart[tile];
  const int nrows = tnr[tile];

  __shared__ unsigned short ldsA[TILE * LDA];
  __shared__ unsigned short ldsT[TILE * LDT];
  __shared__ int srow[TILE];

  const int lane = threadIdx.x & 63;
  const int wave = threadIdx.x >> 6;
  const int wcol0 = wave * 64;
  const int r0 = lane & 15;
  const int kg = (lane >> 4) * 8;
  const int rb = (lane >> 4) * 4;

  if (threadIdx.x < TILE)
    srow[threadIdx.x] = (threadIdx.x < nrows) ? ridx[ts + threadIdx.x] : -1;
  __syncthreads();

  const f32x4 vzero = {0.f, 0.f, 0.f, 0.f};
  f32x4 accO[4][4];
#pragma unroll
  for (int a = 0; a < 4; ++a)
#pragma unroll
    for (int b = 0; b < 4; ++b) accO[a][b] = vzero;

  do_path<DN, LDA>(n1, W1t + (size_t)t1 * 65536, b1 + t1 * 256, Ut, srow, ldsA,
                   ldsT, accO, r0, kg, rb, wave, wcol0);
  do_path<DN, LDA>(n2, W2t + (size_t)t2 * 65536, b2 + t2 * 256, Ut + 65536, srow,
                   ldsA, ldsT, accO, r0, kg, rb, wave, wcol0);
  do_path<DE, LDE>(eg, Wet, be, Ut + 2 * 65536, srow, ldsA, ldsT, accO, r0, kg,
                   rb, wave, wcol0);

  // ---- epilogue: relu(accO + bout) -> scattered rows
#pragma unroll
  for (int cs = 0; cs < 4; ++cs) {
    int col = wcol0 + cs * 16 + r0;
    float bo = bout[col];
#pragma unroll
    for (int rs = 0; rs < 4; ++rs)
#pragma unroll
      for (int i = 0; i < 4; ++i) {
        int row = rs * 16 + rb + i;
        if (row < nrows) {
          float v = fmaxf(accO[rs][cs][i] + bo, 0.f);
          out[(size_t)srow[row] * 256 + col] = v;
        }
      }
  }
}

// ---------------- launcher ----------------
extern "C" void kernel_launch(void* const* d_in, const int* in_sizes, int n_in,
                              void* d_out, int out_size, void* d_ws, size_t ws_size,
                              hipStream_t stream) {
  const float* n1   = (const float*)d_in[0];
  const float* n2   = (const float*)d_in[1];
  const float* eg   = (const float*)d_in[2];
  const int*   ty1  = (const int*)d_in[3];
  const int*   ty2  = (const int*)d_in[4];
  const float* W1   = (const float*)d_in[5];
  const float* b1   = (const float*)d_in[6];
  const float* W2   = (const float*)d_in[7];
  const float* b2   = (const float*)d_in[8];
  const float* We   = (const float*)d_in[9];
  const float* be   = (const float*)d_in[10];
  const float* Wout = (const float*)d_in[11];
  const float* bout = (const float*)d_in[12];
  float* out = (float*)d_out;

  const int N = in_sizes[0] / DN;
  const int maxt = (N + TILE - 1) / TILE + PAIRS;

  char* ws = (char*)d_ws;
  size_t off = 0;
  auto take = [&](size_t bytes) -> char* {
    char* p = ws + off;
    off += (bytes + 255) & ~(size_t)255;
    return p;
  };
  int* cnt = (int*)take(PAIRS * 4);
  int* c2  = (int*)take(PAIRS * 4);
  int* ntl = (int*)take(4);
  int* seg = (int*)take((PAIRS + 1) * 4);
  int* tp  = (int*)take((size_t)maxt * 4);
  int* tst = (int*)take((size_t)maxt * 4);
  int* tnr = (int*)take((size_t)maxt * 4);
  int* ridx = (int*)take((size_t)N * 4);
  unsigned short* W1t = (unsigned short*)take((size_t)J_TYPES * 65536 * 2);
  unsigned short* W2t = (unsigned short*)take((size_t)J_TYPES * 65536 * 2);
  unsigned short* Wet = (unsigned short*)take((size_t)DE * DO * 2);
  unsigned short* Ut  = (unsigned short*)take((size_t)3 * 65536 * 2);
  (void)ws_size; (void)n_in; (void)out_size;

  hipMemsetAsync(cnt, 0, (size_t)((char*)seg - (char*)cnt), stream);
  prep_w_k<<<1024, 256, 0, stream>>>(W1, W2, We, Wout, W1t, W2t, Wet, Ut);
  hist_k<<<400, 256, 0, stream>>>(ty1, ty2, cnt, N);
  scan_tiles_k<<<1, 512, 0, stream>>>(cnt, seg, tp, tst, tnr, ntl);
  scatter_k<<<256, 256, 0, stream>>>(ty1, ty2, seg, c2, ridx, N);
  fused_k<<<maxt, 256, 0, stream>>>(n1, n2, eg, W1t, W2t, Wet, Ut, b1, b2, be, bout,
                                    ridx, tp, tst, tnr, ntl, out);
}

// Round 3
// 526.037 us; speedup vs baseline: 1.2479x; 1.0209x over previous
//
#include <hip/hip_runtime.h>

// TypeAwareEdgeUpdate: out = relu(relu(cat[n1@W1[t1]+b1, n2@W2[t2]+b2, e@We+be]) @ Wout + bout)
// Counting-sort rows by (t1,t2) -> 64-row tiles share weights -> fused bf16 MFMA.
// R3: SGPR-based batched stage gather (8 float4 in flight, scalar ridx loads),
//     fully-unrolled gemm k-loops (B-load hoisting), srow only for epilogue.

#define J_TYPES 17
#define PAIRS   (J_TYPES * J_TYPES)
#define DN      256
#define DE      128
#define DO      256
#define TILE    64
#define LDA     264   // ldsA stride (shorts) for K=256
#define LDE     136   // ldsA stride for K=128 (edge path)
#define LDT     136   // ldsT stride (128 cols + pad)

typedef short bf16x8 __attribute__((ext_vector_type(8)));
typedef float f32x4  __attribute__((ext_vector_type(4)));

__device__ __forceinline__ unsigned short f2bf(float x) {
  unsigned u = __float_as_uint(x);
  return (unsigned short)((u + 0x7fffu + ((u >> 16) & 1u)) >> 16);  // RNE
}

__device__ __forceinline__ unsigned cvtpk(float lo, float hi) {
  unsigned r;
  asm("v_cvt_pk_bf16_f32 %0, %1, %2" : "=v"(r) : "v"(lo), "v"(hi));
  return r;  // lo16 = bf16(lo), hi16 = bf16(hi), RNE
}

// ---------------- weight prep: bf16 + transpose to [out][in] ----------------
__global__ void prep_w_k(const float* __restrict__ W1, const float* __restrict__ W2,
                         const float* __restrict__ We, const float* __restrict__ Wout,
                         unsigned short* __restrict__ W1t, unsigned short* __restrict__ W2t,
                         unsigned short* __restrict__ Wet, unsigned short* __restrict__ Ut) {
  const int SZW = J_TYPES * 65536;
  const int total = SZW * 2 + DE * DO + 3 * 65536;
  for (int i = blockIdx.x * blockDim.x + threadIdx.x; i < total;
       i += gridDim.x * blockDim.x) {
    int idx = i;
    if (idx < SZW) {                       // W1t[j][n][k] = W1[j][k][n]
      int j = idx >> 16, r = idx & 65535, n = r >> 8, k = r & 255;
      W1t[idx] = f2bf(W1[(size_t)(j * 256 + k) * 256 + n]);
    } else if ((idx -= SZW) < SZW) {       // W2t
      int j = idx >> 16, r = idx & 65535, n = r >> 8, k = r & 255;
      W2t[idx] = f2bf(W2[(size_t)(j * 256 + k) * 256 + n]);
    } else if ((idx -= SZW) < DE * DO) {   // Wet[n][k] = We[k][n]
      int n = idx >> 7, k = idx & 127;
      Wet[idx] = f2bf(We[k * 256 + n]);
    } else {                               // Ut[p][n][k] = Wout[p*256+k][n]
      idx -= DE * DO;
      int p = idx >> 16, r = idx & 65535, n = r >> 8, k = r & 255;
      Ut[idx] = f2bf(Wout[(size_t)(p * 256 + k) * 256 + n]);
    }
  }
}

// ---------------- counting sort by pair ----------------
__global__ void hist_k(const int* __restrict__ ty1, const int* __restrict__ ty2,
                       int* __restrict__ cnt, int N) {
  __shared__ int h[PAIRS];
  for (int i = threadIdx.x; i < PAIRS; i += blockDim.x) h[i] = 0;
  __syncthreads();
  for (int i = blockIdx.x * blockDim.x + threadIdx.x; i < N;
       i += gridDim.x * blockDim.x)
    atomicAdd(&h[ty1[i] * J_TYPES + ty2[i]], 1);
  __syncthreads();
  for (int i = threadIdx.x; i < PAIRS; i += blockDim.x) {
    int v = h[i];
    if (v) atomicAdd(&cnt[i], v);
  }
}

__global__ void scan_tiles_k(const int* __restrict__ cnt, int* __restrict__ seg,
                             int* __restrict__ tpair, int* __restrict__ tstart,
                             int* __restrict__ tnr, int* __restrict__ ntl) {
  __shared__ int s1[512], s2[512];
  int t = threadIdx.x;                               // 512 threads
  int c  = (t < PAIRS) ? cnt[t] : 0;
  int nt = (c + TILE - 1) / TILE;
  s1[t] = c; s2[t] = nt;
  __syncthreads();
  for (int o = 1; o < 512; o <<= 1) {                // Hillis-Steele inclusive
    int v1 = (t >= o) ? s1[t - o] : 0;
    int v2 = (t >= o) ? s2[t - o] : 0;
    __syncthreads();
    s1[t] += v1; s2[t] += v2;
    __syncthreads();
  }
  if (t < PAIRS) {
    int segstart = s1[t] - c;
    int tbase    = s2[t] - nt;
    seg[t] = segstart;
    for (int i = 0; i < nt; ++i) {
      tpair[tbase + i]  = t;
      tstart[tbase + i] = segstart + i * TILE;
      int rem = c - i * TILE;
      tnr[tbase + i] = rem < TILE ? rem : TILE;
    }
  }
  if (t == 511) ntl[0] = s2[511];
}

// block-aggregated scatter: one global atomic per (block,pair)
__global__ void scatter_k(const int* __restrict__ ty1, const int* __restrict__ ty2,
                          const int* __restrict__ seg, int* __restrict__ c2,
                          int* __restrict__ ridx, int N) {
  __shared__ int lh[PAIRS], lb[PAIRS];
  int chunk = (N + gridDim.x - 1) / gridDim.x;
  int lo = blockIdx.x * chunk;
  int hi = lo + chunk; if (hi > N) hi = N;
  for (int i = threadIdx.x; i < PAIRS; i += blockDim.x) lh[i] = 0;
  __syncthreads();
  for (int i = lo + threadIdx.x; i < hi; i += blockDim.x)
    atomicAdd(&lh[ty1[i] * J_TYPES + ty2[i]], 1);
  __syncthreads();
  for (int i = threadIdx.x; i < PAIRS; i += blockDim.x) {
    int v = lh[i];
    lb[i] = v ? atomicAdd(&c2[i], v) : 0;
    lh[i] = 0;
  }
  __syncthreads();
  for (int i = lo + threadIdx.x; i < hi; i += blockDim.x) {
    int p = ty1[i] * J_TYPES + ty2[i];
    int pos = seg[p] + lb[p] + atomicAdd(&lh[p], 1);
    ridx[pos] = i;
  }
}

// ---------------- fused tile kernel ----------------
// 4 waves/block. tmp computed in two 128-col halves:
//   gemm1: wave w computes tmp[64][h*128 + w*32 .. +32)   (accT = 8 frags)
//   gemm2: wave w computes accO[64][w*64 .. +64) over k-half (accO = 16 frags)
// A-frag: lane l -> row (l&15), k = (l>>4)*8..+7 ; B-frag: col (l&15), k contig
// D-frag: col = l&15, row = (l>>4)*4 + reg

// Stage: one wave per row (rows wave+4j). Row index is wave-uniform -> scalar
// ridx loads; 8 gathered float4 loads batched in flight. Padding rows are
// clamped to a valid row (garbage never crosses rows; epilogue masks them).
__device__ __forceinline__ void stage256(const float* __restrict__ src,
                                         const int* __restrict__ ridxp, int nrows,
                                         unsigned short* lds, int wave, int lane) {
#pragma unroll
  for (int half = 0; half < 2; ++half) {
    float4 f[8];
#pragma unroll
    for (int j = 0; j < 8; ++j) {
      int r = wave + 4 * (half * 8 + j);
      int rc = r < nrows ? r : nrows - 1;          // uniform clamp
      int sr = ridxp[rc];                          // scalar load
      f[j] = reinterpret_cast<const float4*>(src + (size_t)sr * DN)[lane];
    }
#pragma unroll
    for (int j = 0; j < 8; ++j) {
      int r = wave + 4 * (half * 8 + j);
      unsigned lo = cvtpk(f[j].x, f[j].y), hi = cvtpk(f[j].z, f[j].w);
      *reinterpret_cast<uint2*>(lds + r * LDA + lane * 4) = make_uint2(lo, hi);
    }
  }
}

__device__ __forceinline__ void stage128(const float* __restrict__ src,
                                         const int* __restrict__ ridxp, int nrows,
                                         unsigned short* lds, int wave, int lane) {
#pragma unroll
  for (int half = 0; half < 2; ++half) {
    float2 f[8];
#pragma unroll
    for (int j = 0; j < 8; ++j) {
      int r = wave + 4 * (half * 8 + j);
      int rc = r < nrows ? r : nrows - 1;
      int sr = ridxp[rc];
      f[j] = reinterpret_cast<const float2*>(src + (size_t)sr * DE)[lane];
    }
#pragma unroll
    for (int j = 0; j < 8; ++j) {
      int r = wave + 4 * (half * 8 + j);
      *reinterpret_cast<unsigned*>(lds + r * LDE + lane * 2) = cvtpk(f[j].x, f[j].y);
    }
  }
}

template <int K, int LD>
__device__ __forceinline__ void gemm1(const unsigned short* ldsA,
                                      const unsigned short* __restrict__ Wp,
                                      f32x4 accT[4][2], int r0, int kg, int colbase) {
  const unsigned short* wp0 = Wp + (size_t)colbase * K + kg;
  const unsigned short* wp1 = wp0 + (size_t)16 * K;
#pragma unroll
  for (int kk = 0; kk < K; kk += 32) {
    bf16x8 bf0 = *reinterpret_cast<const bf16x8*>(wp0 + kk);
    bf16x8 bf1 = *reinterpret_cast<const bf16x8*>(wp1 + kk);
    bf16x8 af[4];
#pragma unroll
    for (int rs = 0; rs < 4; ++rs)
      af[rs] = *reinterpret_cast<const bf16x8*>(ldsA + (rs * 16 + r0) * LD + kk + kg);
#pragma unroll
    for (int rs = 0; rs < 4; ++rs) {
      accT[rs][0] = __builtin_amdgcn_mfma_f32_16x16x32_bf16(af[rs], bf0, accT[rs][0], 0, 0, 0);
      accT[rs][1] = __builtin_amdgcn_mfma_f32_16x16x32_bf16(af[rs], bf1, accT[rs][1], 0, 0, 0);
    }
  }
}

__device__ __forceinline__ void epi_half(f32x4 accT[4][2], const float* __restrict__ bias,
                                         unsigned short* ldsT, int r0, int rb,
                                         int wave, int h) {
#pragma unroll
  for (int cs = 0; cs < 2; ++cs) {
    int col_l = wave * 32 + cs * 16 + r0;
    float b = bias[h * 128 + col_l];
#pragma unroll
    for (int rs = 0; rs < 4; ++rs) {
      float x0 = fmaxf(accT[rs][cs][0] + b, 0.f);
      float x1 = fmaxf(accT[rs][cs][1] + b, 0.f);
      float x2 = fmaxf(accT[rs][cs][2] + b, 0.f);
      float x3 = fmaxf(accT[rs][cs][3] + b, 0.f);
      unsigned w01 = cvtpk(x0, x1), w23 = cvtpk(x2, x3);
      int row = rs * 16 + rb;
      ldsT[(row + 0) * LDT + col_l] = (unsigned short)w01;
      ldsT[(row + 1) * LDT + col_l] = (unsigned short)(w01 >> 16);
      ldsT[(row + 2) * LDT + col_l] = (unsigned short)w23;
      ldsT[(row + 3) * LDT + col_l] = (unsigned short)(w23 >> 16);
    }
  }
}

__device__ __forceinline__ void gemm2(const unsigned short* ldsT,
                                      const unsigned short* __restrict__ Up,
                                      f32x4 accO[4][4], int r0, int kg, int wcol0,
                                      int h) {
  const unsigned short* up = Up + (size_t)(wcol0 + r0) * 256 + h * 128 + kg;
#pragma unroll
  for (int kk = 0; kk < 128; kk += 32) {
    bf16x8 bf[4];
#pragma unroll
    for (int cs = 0; cs < 4; ++cs)
      bf[cs] = *reinterpret_cast<const bf16x8*>(up + (size_t)cs * 16 * 256 + kk);
    bf16x8 af[4];
#pragma unroll
    for (int rs = 0; rs < 4; ++rs)
      af[rs] = *reinterpret_cast<const bf16x8*>(ldsT + (rs * 16 + r0) * LDT + kk + kg);
#pragma unroll
    for (int rs = 0; rs < 4; ++rs)
#pragma unroll
      for (int cs = 0; cs < 4; ++cs)
        accO[rs][cs] = __builtin_amdgcn_mfma_f32_16x16x32_bf16(af[rs], bf[cs],
                                                               accO[rs][cs], 0, 0, 0);
  }
}

template <int K, int LD>
__device__ __forceinline__ void do_path(const float* __restrict__ X,
                                        const unsigned short* __restrict__ Wp,
                                        const float* __restrict__ bias,
                                        const unsigned short* __restrict__ Up,
                                        const int* __restrict__ ridxp, int nrows,
                                        unsigned short* ldsA, unsigned short* ldsT,
                                        f32x4 accO[4][4], int r0, int kg, int rb,
                                        int wave, int lane, int wcol0) {
  if (K == DN) stage256(X, ridxp, nrows, ldsA, wave, lane);
  else         stage128(X, ridxp, nrows, ldsA, wave, lane);
  __syncthreads();
#pragma unroll
  for (int h = 0; h < 2; ++h) {
    f32x4 accT[4][2];
    const f32x4 vz = {0.f, 0.f, 0.f, 0.f};
#pragma unroll
    for (int a = 0; a < 4; ++a) { accT[a][0] = vz; accT[a][1] = vz; }
    gemm1<K, LD>(ldsA, Wp, accT, r0, kg, h * 128 + wave * 32 + r0);
    __syncthreads();   // prior ldsT readers (prev gemm2) done
    epi_half(accT, bias, ldsT, r0, rb, wave, h);
    __syncthreads();   // ldsT visible to all
    gemm2(ldsT, Up, accO, r0, kg, wcol0, h);
    // no barrier: next gemm1 reads only ldsA; next epi is barrier-protected
  }
}

__global__ __launch_bounds__(256, 3) void fused_k(
    const float* __restrict__ n1, const float* __restrict__ n2,
    const float* __restrict__ eg, const unsigned short* __restrict__ W1t,
    const unsigned short* __restrict__ W2t, const unsigned short* __restrict__ Wet,
    const unsigned short* __restrict__ Ut, const float* __restrict__ b1,
    const float* __restrict__ b2, const float* __restrict__ be,
    const float* __restrict__ bout, const int* __restrict__ ridx,
    const int* __restrict__ tpair, const int* __restrict__ tstart,
    const int* __restrict__ tnr, const int* __restrict__ ntl,
    float* __restrict__ out) {
  // bijective XCD swizzle: same-pair tiles (consecutive) -> same XCD's L2
  int nwg = gridDim.x, orig = blockIdx.x;
  int q = nwg >> 3, rr = nwg & 7, xc = orig & 7, sidx = orig >> 3;
  int tile = (xc < rr ? xc * (q + 1) : rr * (q + 1) + (xc - rr) * q) + sidx;
  if (tile >= ntl[0]) return;

  const int pr = tpair[tile];
  const int t1 = pr / J_TYPES, t2 = pr % J_TYPES;
  const int ts = tstart[tile];
  const int nrows = tnr[tile];
  const int* __restrict__ ridxp = ridx + ts;

  __shared__ unsigned short ldsA[TILE * LDA];
  __shared__ unsigned short ldsT[TILE * LDT];
  __shared__ int srow[TILE];

  const int lane = threadIdx.x & 63;
  const int wave = __builtin_amdgcn_readfirstlane(threadIdx.x >> 6);
  const int wcol0 = wave * 64;
  const int r0 = lane & 15;
  const int kg = (lane >> 4) * 8;
  const int rb = (lane >> 4) * 4;

  if (threadIdx.x < TILE)
    srow[threadIdx.x] = (threadIdx.x < nrows) ? ridxp[threadIdx.x] : -1;
  // no barrier needed here: srow used only in epilogue (many barriers between)

  const f32x4 vzero = {0.f, 0.f, 0.f, 0.f};
  f32x4 accO[4][4];
#pragma unroll
  for (int a = 0; a < 4; ++a)
#pragma unroll
    for (int b = 0; b < 4; ++b) accO[a][b] = vzero;

  do_path<DN, LDA>(n1, W1t + (size_t)t1 * 65536, b1 + t1 * 256, Ut, ridxp, nrows,
                   ldsA, ldsT, accO, r0, kg, rb, wave, lane, wcol0);
  do_path<DN, LDA>(n2, W2t + (size_t)t2 * 65536, b2 + t2 * 256, Ut + 65536, ridxp,
                   nrows, ldsA, ldsT, accO, r0, kg, rb, wave, lane, wcol0);
  do_path<DE, LDE>(eg, Wet, be, Ut + 2 * 65536, ridxp, nrows, ldsA, ldsT, accO,
                   r0, kg, rb, wave, lane, wcol0);

  // ---- epilogue: relu(accO + bout) -> scattered rows
#pragma unroll
  for (int cs = 0; cs < 4; ++cs) {
    int col = wcol0 + cs * 16 + r0;
    float bo = bout[col];
#pragma unroll
    for (int rs = 0; rs < 4; ++rs)
#pragma unroll
      for (int i = 0; i < 4; ++i) {
        int row = rs * 16 + rb + i;
        if (row < nrows) {
          float v = fmaxf(accO[rs][cs][i] + bo, 0.f);
          out[(size_t)srow[row] * 256 + col] = v;
        }
      }
  }
}

// ---------------- launcher ----------------
extern "C" void kernel_launch(void* const* d_in, const int* in_sizes, int n_in,
                              void* d_out, int out_size, void* d_ws, size_t ws_size,
                              hipStream_t stream) {
  const float* n1   = (const float*)d_in[0];
  const float* n2   = (const float*)d_in[1];
  const float* eg   = (const float*)d_in[2];
  const int*   ty1  = (const int*)d_in[3];
  const int*   ty2  = (const int*)d_in[4];
  const float* W1   = (const float*)d_in[5];
  const float* b1   = (const float*)d_in[6];
  const float* W2   = (const float*)d_in[7];
  const float* b2   = (const float*)d_in[8];
  const float* We   = (const float*)d_in[9];
  const float* be   = (const float*)d_in[10];
  const float* Wout = (const float*)d_in[11];
  const float* bout = (const float*)d_in[12];
  float* out = (float*)d_out;

  const int N = in_sizes[0] / DN;
  const int maxt = (N + TILE - 1) / TILE + PAIRS;

  char* ws = (char*)d_ws;
  size_t off = 0;
  auto take = [&](size_t bytes) -> char* {
    char* p = ws + off;
    off += (bytes + 255) & ~(size_t)255;
    return p;
  };
  int* cnt = (int*)take(PAIRS * 4);
  int* c2  = (int*)take(PAIRS * 4);
  int* ntl = (int*)take(4);
  int* seg = (int*)take((PAIRS + 1) * 4);
  int* tp  = (int*)take((size_t)maxt * 4);
  int* tst = (int*)take((size_t)maxt * 4);
  int* tnr = (int*)take((size_t)maxt * 4);
  int* ridx = (int*)take((size_t)N * 4);
  unsigned short* W1t = (unsigned short*)take((size_t)J_TYPES * 65536 * 2);
  unsigned short* W2t = (unsigned short*)take((size_t)J_TYPES * 65536 * 2);
  unsigned short* Wet = (unsigned short*)take((size_t)DE * DO * 2);
  unsigned short* Ut  = (unsigned short*)take((size_t)3 * 65536 * 2);
  (void)ws_size; (void)n_in; (void)out_size;

  hipMemsetAsync(cnt, 0, (size_t)((char*)seg - (char*)cnt), stream);
  prep_w_k<<<1024, 256, 0, stream>>>(W1, W2, We, Wout, W1t, W2t, Wet, Ut);
  hist_k<<<400, 256, 0, stream>>>(ty1, ty2, cnt, N);
  scan_tiles_k<<<1, 512, 0, stream>>>(cnt, seg, tp, tst, tnr, ntl);
  scatter_k<<<256, 256, 0, stream>>>(ty1, ty2, seg, c2, ridx, N);
  fused_k<<<maxt, 256, 0, stream>>>(n1, n2, eg, W1t, W2t, Wet, Ut, b1, b2, be, bout,
                                    ridx, tp, tst, tnr, ntl, out);
}

// Round 4
// 362.591 us; speedup vs baseline: 1.8104x; 1.4508x over previous
//
#include <hip/hip_runtime.h>

// TypeAwareEdgeUpdate: out = relu(relu(cat[n1@W1[t1]+b1, n2@W2[t2]+b2, e@We+be]) @ Wout + bout)
// Counting-sort rows by (t1,t2) -> 64-row tiles share weights -> fused bf16 MFMA.
// R4: FRAGMENT-NATIVE weight layout. Weights stored as [colt][k32][lane][8] so each
// B-fragment load is one contiguous 1KB wave load (was a 16-segment gather).

#define J_TYPES 17
#define PAIRS   (J_TYPES * J_TYPES)
#define DN      256
#define DE      128
#define DO      256
#define TILE    64
#define LDA     264   // ldsA stride (shorts) for K=256
#define LDE     136   // ldsA stride for K=128 (edge path)
#define LDT     136   // ldsT stride (128 cols + pad)

typedef short bf16x8 __attribute__((ext_vector_type(8)));
typedef float f32x4  __attribute__((ext_vector_type(4)));

__device__ __forceinline__ unsigned short f2bf(float x) {
  unsigned u = __float_as_uint(x);
  return (unsigned short)((u + 0x7fffu + ((u >> 16) & 1u)) >> 16);  // RNE
}

__device__ __forceinline__ unsigned cvtpk(float lo, float hi) {
  unsigned r;
  asm("v_cvt_pk_bf16_f32 %0, %1, %2" : "=v"(r) : "v"(lo), "v"(hi));
  return r;  // lo16 = bf16(lo), hi16 = bf16(hi), RNE
}

// ---------------- weight prep: bf16, fragment-native layout ----------------
// Layout per matrix: [colt][k32][lane][i] (shorts), element (col,k):
//   col = colt*16 + (lane&15), k = k32*32 + (lane>>4)*8 + i
// One (colt,k32) tile = 512 shorts = 1KB; a wave's B-frag load = tile + lane*8.
__global__ void prep_w_k(const float* __restrict__ W1, const float* __restrict__ W2,
                         const float* __restrict__ We, const float* __restrict__ Wout,
                         unsigned short* __restrict__ W1t, unsigned short* __restrict__ W2t,
                         unsigned short* __restrict__ Wet, unsigned short* __restrict__ Ut) {
  const int SZW = J_TYPES * 65536;
  const int total = SZW * 2 + DE * DO + 3 * 65536;
  for (int o = blockIdx.x * blockDim.x + threadIdx.x; o < total;
       o += gridDim.x * blockDim.x) {
    int idx = o;
    if (idx < SZW) {                       // W1 frag-native, K=256
      int j = idx >> 16, r = idx & 65535;
      int i = r & 7, lane = (r >> 3) & 63, t = r >> 9;
      int k32 = t & 7, colt = t >> 3;
      int col = colt * 16 + (lane & 15);
      int k = k32 * 32 + ((lane >> 4) << 3) + i;
      W1t[idx] = f2bf(W1[((size_t)j * 256 + k) * 256 + col]);
    } else if ((idx -= SZW) < SZW) {       // W2
      int j = idx >> 16, r = idx & 65535;
      int i = r & 7, lane = (r >> 3) & 63, t = r >> 9;
      int k32 = t & 7, colt = t >> 3;
      int col = colt * 16 + (lane & 15);
      int k = k32 * 32 + ((lane >> 4) << 3) + i;
      W2t[idx] = f2bf(W2[((size_t)j * 256 + k) * 256 + col]);
    } else if ((idx -= SZW) < DE * DO) {   // We, K=128 (4 k32-tiles per colt)
      int r = idx;
      int i = r & 7, lane = (r >> 3) & 63, t = r >> 9;
      int k32 = t & 3, colt = t >> 2;
      int col = colt * 16 + (lane & 15);
      int k = k32 * 32 + ((lane >> 4) << 3) + i;
      Wet[idx] = f2bf(We[(size_t)k * 256 + col]);
    } else {                               // Wout (3 stacked K=256 matrices)
      idx -= DE * DO;
      int p = idx >> 16, r = idx & 65535;
      int i = r & 7, lane = (r >> 3) & 63, t = r >> 9;
      int k32 = t & 7, colt = t >> 3;
      int col = colt * 16 + (lane & 15);
      int k = k32 * 32 + ((lane >> 4) << 3) + i;
      Ut[idx] = f2bf(Wout[((size_t)p * 256 + k) * 256 + col]);
    }
  }
}

// ---------------- counting sort by pair ----------------
__global__ void hist_k(const int* __restrict__ ty1, const int* __restrict__ ty2,
                       int* __restrict__ cnt, int N) {
  __shared__ int h[PAIRS];
  for (int i = threadIdx.x; i < PAIRS; i += blockDim.x) h[i] = 0;
  __syncthreads();
  for (int i = blockIdx.x * blockDim.x + threadIdx.x; i < N;
       i += gridDim.x * blockDim.x)
    atomicAdd(&h[ty1[i] * J_TYPES + ty2[i]], 1);
  __syncthreads();
  for (int i = threadIdx.x; i < PAIRS; i += blockDim.x) {
    int v = h[i];
    if (v) atomicAdd(&cnt[i], v);
  }
}

__global__ void scan_tiles_k(const int* __restrict__ cnt, int* __restrict__ seg,
                             int* __restrict__ tpair, int* __restrict__ tstart,
                             int* __restrict__ tnr, int* __restrict__ ntl) {
  __shared__ int s1[512], s2[512];
  int t = threadIdx.x;                               // 512 threads
  int c  = (t < PAIRS) ? cnt[t] : 0;
  int nt = (c + TILE - 1) / TILE;
  s1[t] = c; s2[t] = nt;
  __syncthreads();
  for (int o = 1; o < 512; o <<= 1) {                // Hillis-Steele inclusive
    int v1 = (t >= o) ? s1[t - o] : 0;
    int v2 = (t >= o) ? s2[t - o] : 0;
    __syncthreads();
    s1[t] += v1; s2[t] += v2;
    __syncthreads();
  }
  if (t < PAIRS) {
    int segstart = s1[t] - c;
    int tbase    = s2[t] - nt;
    seg[t] = segstart;
    for (int i = 0; i < nt; ++i) {
      tpair[tbase + i]  = t;
      tstart[tbase + i] = segstart + i * TILE;
      int rem = c - i * TILE;
      tnr[tbase + i] = rem < TILE ? rem : TILE;
    }
  }
  if (t == 511) ntl[0] = s2[511];
}

// block-aggregated scatter: one global atomic per (block,pair)
__global__ void scatter_k(const int* __restrict__ ty1, const int* __restrict__ ty2,
                          const int* __restrict__ seg, int* __restrict__ c2,
                          int* __restrict__ ridx, int N) {
  __shared__ int lh[PAIRS], lb[PAIRS];
  int chunk = (N + gridDim.x - 1) / gridDim.x;
  int lo = blockIdx.x * chunk;
  int hi = lo + chunk; if (hi > N) hi = N;
  for (int i = threadIdx.x; i < PAIRS; i += blockDim.x) lh[i] = 0;
  __syncthreads();
  for (int i = lo + threadIdx.x; i < hi; i += blockDim.x)
    atomicAdd(&lh[ty1[i] * J_TYPES + ty2[i]], 1);
  __syncthreads();
  for (int i = threadIdx.x; i < PAIRS; i += blockDim.x) {
    int v = lh[i];
    lb[i] = v ? atomicAdd(&c2[i], v) : 0;
    lh[i] = 0;
  }
  __syncthreads();
  for (int i = lo + threadIdx.x; i < hi; i += blockDim.x) {
    int p = ty1[i] * J_TYPES + ty2[i];
    int pos = seg[p] + lb[p] + atomicAdd(&lh[p], 1);
    ridx[pos] = i;
  }
}

// ---------------- fused tile kernel ----------------
// 4 waves/block. tmp computed in two 128-col halves:
//   gemm1: wave w computes tmp[64][h*128 + w*32 .. +32)   (accT = 8 frags)
//   gemm2: wave w computes accO[64][w*64 .. +64) over k-half (accO = 16 frags)
// A-frag from LDS; B-frag = one contiguous 1KB load from frag-native weights.

__device__ __forceinline__ void stage256(const float* __restrict__ src,
                                         const int* __restrict__ ridxp, int nrows,
                                         unsigned short* lds, int wave, int lane) {
#pragma unroll
  for (int half = 0; half < 2; ++half) {
    float4 f[8];
#pragma unroll
    for (int j = 0; j < 8; ++j) {
      int r = wave + 4 * (half * 8 + j);
      int rc = r < nrows ? r : nrows - 1;          // uniform clamp
      int sr = ridxp[rc];                          // scalar load
      f[j] = reinterpret_cast<const float4*>(src + (size_t)sr * DN)[lane];
    }
#pragma unroll
    for (int j = 0; j < 8; ++j) {
      int r = wave + 4 * (half * 8 + j);
      unsigned lo = cvtpk(f[j].x, f[j].y), hi = cvtpk(f[j].z, f[j].w);
      *reinterpret_cast<uint2*>(lds + r * LDA + lane * 4) = make_uint2(lo, hi);
    }
  }
}

__device__ __forceinline__ void stage128(const float* __restrict__ src,
                                         const int* __restrict__ ridxp, int nrows,
                                         unsigned short* lds, int wave, int lane) {
#pragma unroll
  for (int half = 0; half < 2; ++half) {
    float2 f[8];
#pragma unroll
    for (int j = 0; j < 8; ++j) {
      int r = wave + 4 * (half * 8 + j);
      int rc = r < nrows ? r : nrows - 1;
      int sr = ridxp[rc];
      f[j] = reinterpret_cast<const float2*>(src + (size_t)sr * DE)[lane];
    }
#pragma unroll
    for (int j = 0; j < 8; ++j) {
      int r = wave + 4 * (half * 8 + j);
      *reinterpret_cast<unsigned*>(lds + r * LDE + lane * 2) = cvtpk(f[j].x, f[j].y);
    }
  }
}

// Wp: frag-native weight base for this path. colt = 16-col tile index.
template <int K, int LD>
__device__ __forceinline__ void gemm1(const unsigned short* ldsA,
                                      const unsigned short* __restrict__ Wp,
                                      f32x4 accT[4][2], int r0, int kg, int lane,
                                      int colt0) {
  constexpr int NK = K / 32;
  const unsigned short* w0 = Wp + ((size_t)colt0 * NK) * 512 + lane * 8;
  const unsigned short* w1 = w0 + (size_t)NK * 512;
#pragma unroll
  for (int k32 = 0; k32 < NK; ++k32) {
    bf16x8 bf0 = *reinterpret_cast<const bf16x8*>(w0 + k32 * 512);
    bf16x8 bf1 = *reinterpret_cast<const bf16x8*>(w1 + k32 * 512);
    bf16x8 af[4];
#pragma unroll
    for (int rs = 0; rs < 4; ++rs)
      af[rs] = *reinterpret_cast<const bf16x8*>(ldsA + (rs * 16 + r0) * LD + k32 * 32 + kg);
#pragma unroll
    for (int rs = 0; rs < 4; ++rs) {
      accT[rs][0] = __builtin_amdgcn_mfma_f32_16x16x32_bf16(af[rs], bf0, accT[rs][0], 0, 0, 0);
      accT[rs][1] = __builtin_amdgcn_mfma_f32_16x16x32_bf16(af[rs], bf1, accT[rs][1], 0, 0, 0);
    }
  }
}

__device__ __forceinline__ void epi_half(f32x4 accT[4][2], const float* __restrict__ bias,
                                         unsigned short* ldsT, int r0, int rb,
                                         int wave, int h) {
#pragma unroll
  for (int cs = 0; cs < 2; ++cs) {
    int col_l = wave * 32 + cs * 16 + r0;
    float b = bias[h * 128 + col_l];
#pragma unroll
    for (int rs = 0; rs < 4; ++rs) {
      float x0 = fmaxf(accT[rs][cs][0] + b, 0.f);
      float x1 = fmaxf(accT[rs][cs][1] + b, 0.f);
      float x2 = fmaxf(accT[rs][cs][2] + b, 0.f);
      float x3 = fmaxf(accT[rs][cs][3] + b, 0.f);
      unsigned w01 = cvtpk(x0, x1), w23 = cvtpk(x2, x3);
      int row = rs * 16 + rb;
      ldsT[(row + 0) * LDT + col_l] = (unsigned short)w01;
      ldsT[(row + 1) * LDT + col_l] = (unsigned short)(w01 >> 16);
      ldsT[(row + 2) * LDT + col_l] = (unsigned short)w23;
      ldsT[(row + 3) * LDT + col_l] = (unsigned short)(w23 >> 16);
    }
  }
}

// Up: frag-native Wout slice for this path (K=256 -> 8 k32-tiles per colt).
__device__ __forceinline__ void gemm2(const unsigned short* ldsT,
                                      const unsigned short* __restrict__ Up,
                                      f32x4 accO[4][4], int r0, int kg, int lane,
                                      int wave, int h) {
  const unsigned short* u = Up + ((size_t)(wave * 4) * 8 + h * 4) * 512 + lane * 8;
#pragma unroll
  for (int k32 = 0; k32 < 4; ++k32) {
    bf16x8 bf[4];
#pragma unroll
    for (int cs = 0; cs < 4; ++cs)
      bf[cs] = *reinterpret_cast<const bf16x8*>(u + ((size_t)cs * 8 + k32) * 512);
    bf16x8 af[4];
#pragma unroll
    for (int rs = 0; rs < 4; ++rs)
      af[rs] = *reinterpret_cast<const bf16x8*>(ldsT + (rs * 16 + r0) * LDT + k32 * 32 + kg);
#pragma unroll
    for (int rs = 0; rs < 4; ++rs)
#pragma unroll
      for (int cs = 0; cs < 4; ++cs)
        accO[rs][cs] = __builtin_amdgcn_mfma_f32_16x16x32_bf16(af[rs], bf[cs],
                                                               accO[rs][cs], 0, 0, 0);
  }
}

template <int K, int LD>
__device__ __forceinline__ void do_path(const float* __restrict__ X,
                                        const unsigned short* __restrict__ Wp,
                                        const float* __restrict__ bias,
                                        const unsigned short* __restrict__ Up,
                                        const int* __restrict__ ridxp, int nrows,
                                        unsigned short* ldsA, unsigned short* ldsT,
                                        f32x4 accO[4][4], int r0, int kg, int rb,
                                        int wave, int lane) {
  if (K == DN) stage256(X, ridxp, nrows, ldsA, wave, lane);
  else         stage128(X, ridxp, nrows, ldsA, wave, lane);
  __syncthreads();
#pragma unroll
  for (int h = 0; h < 2; ++h) {
    f32x4 accT[4][2];
    const f32x4 vz = {0.f, 0.f, 0.f, 0.f};
#pragma unroll
    for (int a = 0; a < 4; ++a) { accT[a][0] = vz; accT[a][1] = vz; }
    gemm1<K, LD>(ldsA, Wp, accT, r0, kg, lane, h * 8 + wave * 2);
    __syncthreads();   // prior ldsT readers (prev gemm2) done
    epi_half(accT, bias, ldsT, r0, rb, wave, h);
    __syncthreads();   // ldsT visible to all
    gemm2(ldsT, Up, accO, r0, kg, lane, wave, h);
    // no barrier: next gemm1 reads only ldsA; next epi is barrier-protected
  }
}

__global__ __launch_bounds__(256, 3) void fused_k(
    const float* __restrict__ n1, const float* __restrict__ n2,
    const float* __restrict__ eg, const unsigned short* __restrict__ W1t,
    const unsigned short* __restrict__ W2t, const unsigned short* __restrict__ Wet,
    const unsigned short* __restrict__ Ut, const float* __restrict__ b1,
    const float* __restrict__ b2, const float* __restrict__ be,
    const float* __restrict__ bout, const int* __restrict__ ridx,
    const int* __restrict__ tpair, const int* __restrict__ tstart,
    const int* __restrict__ tnr, const int* __restrict__ ntl,
    float* __restrict__ out) {
  // bijective XCD swizzle: same-pair tiles (consecutive) -> same XCD's L2
  int nwg = gridDim.x, orig = blockIdx.x;
  int q = nwg >> 3, rr = nwg & 7, xc = orig & 7, sidx = orig >> 3;
  int tile = (xc < rr ? xc * (q + 1) : rr * (q + 1) + (xc - rr) * q) + sidx;
  if (tile >= ntl[0]) return;

  const int pr = tpair[tile];
  const int t1 = pr / J_TYPES, t2 = pr % J_TYPES;
  const int ts = tstart[tile];
  const int nrows = tnr[tile];
  const int* __restrict__ ridxp = ridx + ts;

  __shared__ unsigned short ldsA[TILE * LDA];
  __shared__ unsigned short ldsT[TILE * LDT];
  __shared__ int srow[TILE];

  const int lane = threadIdx.x & 63;
  const int wave = __builtin_amdgcn_readfirstlane(threadIdx.x >> 6);
  const int wcol0 = wave * 64;
  const int r0 = lane & 15;
  const int kg = (lane >> 4) * 8;
  const int rb = (lane >> 4) * 4;

  if (threadIdx.x < TILE)
    srow[threadIdx.x] = (threadIdx.x < nrows) ? ridxp[threadIdx.x] : -1;
  // srow used only in epilogue (many barriers between)

  const f32x4 vzero = {0.f, 0.f, 0.f, 0.f};
  f32x4 accO[4][4];
#pragma unroll
  for (int a = 0; a < 4; ++a)
#pragma unroll
    for (int b = 0; b < 4; ++b) accO[a][b] = vzero;

  do_path<DN, LDA>(n1, W1t + (size_t)t1 * 65536, b1 + t1 * 256, Ut, ridxp, nrows,
                   ldsA, ldsT, accO, r0, kg, rb, wave, lane);
  do_path<DN, LDA>(n2, W2t + (size_t)t2 * 65536, b2 + t2 * 256, Ut + 65536, ridxp,
                   nrows, ldsA, ldsT, accO, r0, kg, rb, wave, lane);
  do_path<DE, LDE>(eg, Wet, be, Ut + 2 * 65536, ridxp, nrows, ldsA, ldsT, accO,
                   r0, kg, rb, wave, lane);

  // ---- epilogue: relu(accO + bout) -> scattered rows
#pragma unroll
  for (int cs = 0; cs < 4; ++cs) {
    int col = wcol0 + cs * 16 + r0;
    float bo = bout[col];
#pragma unroll
    for (int rs = 0; rs < 4; ++rs)
#pragma unroll
      for (int i = 0; i < 4; ++i) {
        int row = rs * 16 + rb + i;
        if (row < nrows) {
          float v = fmaxf(accO[rs][cs][i] + bo, 0.f);
          out[(size_t)srow[row] * 256 + col] = v;
        }
      }
  }
}

// ---------------- launcher ----------------
extern "C" void kernel_launch(void* const* d_in, const int* in_sizes, int n_in,
                              void* d_out, int out_size, void* d_ws, size_t ws_size,
                              hipStream_t stream) {
  const float* n1   = (const float*)d_in[0];
  const float* n2   = (const float*)d_in[1];
  const float* eg   = (const float*)d_in[2];
  const int*   ty1  = (const int*)d_in[3];
  const int*   ty2  = (const int*)d_in[4];
  const float* W1   = (const float*)d_in[5];
  const float* b1   = (const float*)d_in[6];
  const float* W2   = (const float*)d_in[7];
  const float* b2   = (const float*)d_in[8];
  const float* We   = (const float*)d_in[9];
  const float* be   = (const float*)d_in[10];
  const float* Wout = (const float*)d_in[11];
  const float* bout = (const float*)d_in[12];
  float* out = (float*)d_out;

  const int N = in_sizes[0] / DN;
  const int maxt = (N + TILE - 1) / TILE + PAIRS;

  char* ws = (char*)d_ws;
  size_t off = 0;
  auto take = [&](size_t bytes) -> char* {
    char* p = ws + off;
    off += (bytes + 255) & ~(size_t)255;
    return p;
  };
  int* cnt = (int*)take(PAIRS * 4);
  int* c2  = (int*)take(PAIRS * 4);
  int* ntl = (int*)take(4);
  int* seg = (int*)take((PAIRS + 1) * 4);
  int* tp  = (int*)take((size_t)maxt * 4);
  int* tst = (int*)take((size_t)maxt * 4);
  int* tnr = (int*)take((size_t)maxt * 4);
  int* ridx = (int*)take((size_t)N * 4);
  unsigned short* W1t = (unsigned short*)take((size_t)J_TYPES * 65536 * 2);
  unsigned short* W2t = (unsigned short*)take((size_t)J_TYPES * 65536 * 2);
  unsigned short* Wet = (unsigned short*)take((size_t)DE * DO * 2);
  unsigned short* Ut  = (unsigned short*)take((size_t)3 * 65536 * 2);
  (void)ws_size; (void)n_in; (void)out_size;

  hipMemsetAsync(cnt, 0, (size_t)((char*)seg - (char*)cnt), stream);
  prep_w_k<<<1024, 256, 0, stream>>>(W1, W2, We, Wout, W1t, W2t, Wet, Ut);
  hist_k<<<400, 256, 0, stream>>>(ty1, ty2, cnt, N);
  scan_tiles_k<<<1, 512, 0, stream>>>(cnt, seg, tp, tst, tnr, ntl);
  scatter_k<<<256, 256, 0, stream>>>(ty1, ty2, seg, c2, ridx, N);
  fused_k<<<maxt, 256, 0, stream>>>(n1, n2, eg, W1t, W2t, Wet, Ut, b1, b2, be, bout,
                                    ridx, tp, tst, tnr, ntl, out);
}

// Round 5
// 355.312 us; speedup vs baseline: 1.8475x; 1.0205x over previous
//
#include <hip/hip_runtime.h>

// TypeAwareEdgeUpdate: out = relu(relu(cat[n1@W1[t1]+b1, n2@W2[t2]+b2, e@We+be]) @ Wout + bout)
// Counting-sort rows by (t1,t2) -> 64-row tiles share weights -> fused bf16 MFMA.
// R5: 2-phase pipeline. Full-width gemm phases (accT[4][4] per wave), merged
// {epi || stage_write} and {gemm2 || gemm1_next || stage_issue} phases, 8 barriers/block.

#define J_TYPES 17
#define PAIRS   (J_TYPES * J_TYPES)
#define DN      256
#define DE      128
#define DO      256
#define TILE    64
#define LDA     264   // ldsA / ldsT stride (shorts) for 256 cols
#define LDE     136   // ldsA stride for K=128 (edge path)

typedef short bf16x8 __attribute__((ext_vector_type(8)));
typedef float f32x4  __attribute__((ext_vector_type(4)));

__device__ __forceinline__ unsigned short f2bf(float x) {
  unsigned u = __float_as_uint(x);
  return (unsigned short)((u + 0x7fffu + ((u >> 16) & 1u)) >> 16);  // RNE
}

__device__ __forceinline__ unsigned cvtpk(float lo, float hi) {
  unsigned r;
  asm("v_cvt_pk_bf16_f32 %0, %1, %2" : "=v"(r) : "v"(lo), "v"(hi));
  return r;  // lo16 = bf16(lo), hi16 = bf16(hi), RNE
}

// ---------------- weight prep: bf16, fragment-native layout ----------------
// Layout per matrix: [colt][k32][lane][i] (shorts), element (col,k):
//   col = colt*16 + (lane&15), k = k32*32 + (lane>>4)*8 + i
// One (colt,k32) tile = 512 shorts = 1KB; a wave's B-frag load = tile + lane*8.
__global__ void prep_w_k(const float* __restrict__ W1, const float* __restrict__ W2,
                         const float* __restrict__ We, const float* __restrict__ Wout,
                         unsigned short* __restrict__ W1t, unsigned short* __restrict__ W2t,
                         unsigned short* __restrict__ Wet, unsigned short* __restrict__ Ut) {
  const int SZW = J_TYPES * 65536;
  const int total = SZW * 2 + DE * DO + 3 * 65536;
  for (int o = blockIdx.x * blockDim.x + threadIdx.x; o < total;
       o += gridDim.x * blockDim.x) {
    int idx = o;
    if (idx < SZW) {                       // W1 frag-native, K=256
      int j = idx >> 16, r = idx & 65535;
      int i = r & 7, lane = (r >> 3) & 63, t = r >> 9;
      int k32 = t & 7, colt = t >> 3;
      int col = colt * 16 + (lane & 15);
      int k = k32 * 32 + ((lane >> 4) << 3) + i;
      W1t[idx] = f2bf(W1[((size_t)j * 256 + k) * 256 + col]);
    } else if ((idx -= SZW) < SZW) {       // W2
      int j = idx >> 16, r = idx & 65535;
      int i = r & 7, lane = (r >> 3) & 63, t = r >> 9;
      int k32 = t & 7, colt = t >> 3;
      int col = colt * 16 + (lane & 15);
      int k = k32 * 32 + ((lane >> 4) << 3) + i;
      W2t[idx] = f2bf(W2[((size_t)j * 256 + k) * 256 + col]);
    } else if ((idx -= SZW) < DE * DO) {   // We, K=128 (4 k32-tiles per colt)
      int r = idx;
      int i = r & 7, lane = (r >> 3) & 63, t = r >> 9;
      int k32 = t & 3, colt = t >> 2;
      int col = colt * 16 + (lane & 15);
      int k = k32 * 32 + ((lane >> 4) << 3) + i;
      Wet[idx] = f2bf(We[(size_t)k * 256 + col]);
    } else {                               // Wout (3 stacked K=256 matrices)
      idx -= DE * DO;
      int p = idx >> 16, r = idx & 65535;
      int i = r & 7, lane = (r >> 3) & 63, t = r >> 9;
      int k32 = t & 7, colt = t >> 3;
      int col = colt * 16 + (lane & 15);
      int k = k32 * 32 + ((lane >> 4) << 3) + i;
      Ut[idx] = f2bf(Wout[((size_t)p * 256 + k) * 256 + col]);
    }
  }
}

// ---------------- counting sort by pair ----------------
__global__ void hist_k(const int* __restrict__ ty1, const int* __restrict__ ty2,
                       int* __restrict__ cnt, int N) {
  __shared__ int h[PAIRS];
  for (int i = threadIdx.x; i < PAIRS; i += blockDim.x) h[i] = 0;
  __syncthreads();
  for (int i = blockIdx.x * blockDim.x + threadIdx.x; i < N;
       i += gridDim.x * blockDim.x)
    atomicAdd(&h[ty1[i] * J_TYPES + ty2[i]], 1);
  __syncthreads();
  for (int i = threadIdx.x; i < PAIRS; i += blockDim.x) {
    int v = h[i];
    if (v) atomicAdd(&cnt[i], v);
  }
}

__global__ void scan_tiles_k(const int* __restrict__ cnt, int* __restrict__ seg,
                             int* __restrict__ tpair, int* __restrict__ tstart,
                             int* __restrict__ tnr, int* __restrict__ ntl) {
  __shared__ int s1[512], s2[512];
  int t = threadIdx.x;                               // 512 threads
  int c  = (t < PAIRS) ? cnt[t] : 0;
  int nt = (c + TILE - 1) / TILE;
  s1[t] = c; s2[t] = nt;
  __syncthreads();
  for (int o = 1; o < 512; o <<= 1) {                // Hillis-Steele inclusive
    int v1 = (t >= o) ? s1[t - o] : 0;
    int v2 = (t >= o) ? s2[t - o] : 0;
    __syncthreads();
    s1[t] += v1; s2[t] += v2;
    __syncthreads();
  }
  if (t < PAIRS) {
    int segstart = s1[t] - c;
    int tbase    = s2[t] - nt;
    seg[t] = segstart;
    for (int i = 0; i < nt; ++i) {
      tpair[tbase + i]  = t;
      tstart[tbase + i] = segstart + i * TILE;
      int rem = c - i * TILE;
      tnr[tbase + i] = rem < TILE ? rem : TILE;
    }
  }
  if (t == 511) ntl[0] = s2[511];
}

// block-aggregated scatter: one global atomic per (block,pair)
__global__ void scatter_k(const int* __restrict__ ty1, const int* __restrict__ ty2,
                          const int* __restrict__ seg, int* __restrict__ c2,
                          int* __restrict__ ridx, int N) {
  __shared__ int lh[PAIRS], lb[PAIRS];
  int chunk = (N + gridDim.x - 1) / gridDim.x;
  int lo = blockIdx.x * chunk;
  int hi = lo + chunk; if (hi > N) hi = N;
  for (int i = threadIdx.x; i < PAIRS; i += blockDim.x) lh[i] = 0;
  __syncthreads();
  for (int i = lo + threadIdx.x; i < hi; i += blockDim.x)
    atomicAdd(&lh[ty1[i] * J_TYPES + ty2[i]], 1);
  __syncthreads();
  for (int i = threadIdx.x; i < PAIRS; i += blockDim.x) {
    int v = lh[i];
    lb[i] = v ? atomicAdd(&c2[i], v) : 0;
    lh[i] = 0;
  }
  __syncthreads();
  for (int i = lo + threadIdx.x; i < hi; i += blockDim.x) {
    int p = ty1[i] * J_TYPES + ty2[i];
    int pos = seg[p] + lb[p] + atomicAdd(&lh[p], 1);
    ridx[pos] = i;
  }
}

// ---------------- fused tile kernel ----------------
// 4 waves/block, wave w owns cols [w*64, w*64+64) of tmp AND of out.
// A-frag: lane l -> row (l&15)+16rs, k=(l>>4)*8..+7 (b128 from LDS)
// B-frag: contiguous 1KB wave load from frag-native weights
// D-frag: col = l&15, row = (l>>4)*4 + reg

__device__ __forceinline__ void stage_issue256(const float* __restrict__ src,
                                               const int* __restrict__ ridxp, int nrows,
                                               int wave, int lane, float4 f[16]) {
#pragma unroll
  for (int j = 0; j < 16; ++j) {
    int r = wave + 4 * j;
    int rc = r < nrows ? r : nrows - 1;          // uniform clamp
    int sr = ridxp[rc];                          // scalar load
    f[j] = reinterpret_cast<const float4*>(src + (size_t)sr * DN)[lane];
  }
}

__device__ __forceinline__ void stage_write256(const float4 f[16],
                                               unsigned short* lds, int wave, int lane) {
#pragma unroll
  for (int j = 0; j < 16; ++j) {
    int r = wave + 4 * j;
    unsigned lo = cvtpk(f[j].x, f[j].y), hi = cvtpk(f[j].z, f[j].w);
    *reinterpret_cast<uint2*>(lds + r * LDA + lane * 4) = make_uint2(lo, hi);
  }
}

__device__ __forceinline__ void stage_issue128(const float* __restrict__ src,
                                               const int* __restrict__ ridxp, int nrows,
                                               int wave, int lane, float2 f[16]) {
#pragma unroll
  for (int j = 0; j < 16; ++j) {
    int r = wave + 4 * j;
    int rc = r < nrows ? r : nrows - 1;
    int sr = ridxp[rc];
    f[j] = reinterpret_cast<const float2*>(src + (size_t)sr * DE)[lane];
  }
}

__device__ __forceinline__ void stage_write128(const float2 f[16],
                                               unsigned short* lds, int wave, int lane) {
#pragma unroll
  for (int j = 0; j < 16; ++j) {
    int r = wave + 4 * j;
    *reinterpret_cast<unsigned*>(lds + r * LDE + lane * 2) = cvtpk(f[j].x, f[j].y);
  }
}

// Full-width gemm: wave computes 64 rows x 64 cols over K = NK*32.
// Wbase: frag-native matrix base (this wave picks colt = wave*4 + cs).
template <int NK, int LD>
__device__ __forceinline__ void gemm_full(const unsigned short* lds,
                                          const unsigned short* __restrict__ Wbase,
                                          f32x4 acc[4][4], int r0, int kg, int lane,
                                          int wave) {
  const unsigned short* w = Wbase + ((size_t)(wave * 4) * NK) * 512 + lane * 8;
#pragma unroll
  for (int k32 = 0; k32 < NK; ++k32) {
    bf16x8 bf[4];
#pragma unroll
    for (int cs = 0; cs < 4; ++cs)
      bf[cs] = *reinterpret_cast<const bf16x8*>(w + ((size_t)cs * NK + k32) * 512);
    bf16x8 af[4];
#pragma unroll
    for (int rs = 0; rs < 4; ++rs)
      af[rs] = *reinterpret_cast<const bf16x8*>(lds + (rs * 16 + r0) * LD + k32 * 32 + kg);
#pragma unroll
    for (int rs = 0; rs < 4; ++rs)
#pragma unroll
      for (int cs = 0; cs < 4; ++cs)
        acc[rs][cs] = __builtin_amdgcn_mfma_f32_16x16x32_bf16(af[rs], bf[cs],
                                                              acc[rs][cs], 0, 0, 0);
  }
}

// epi: relu(accT + bias) -> bf16 -> ldsT (full 256-col tile, this wave's 64 cols)
__device__ __forceinline__ void epi_full(f32x4 accT[4][4], const float* __restrict__ bias,
                                         unsigned short* ldsT, int r0, int rb, int wave) {
#pragma unroll
  for (int cs = 0; cs < 4; ++cs) {
    int col = wave * 64 + cs * 16 + r0;
    float b = bias[col];
#pragma unroll
    for (int rs = 0; rs < 4; ++rs) {
      float x0 = fmaxf(accT[rs][cs][0] + b, 0.f);
      float x1 = fmaxf(accT[rs][cs][1] + b, 0.f);
      float x2 = fmaxf(accT[rs][cs][2] + b, 0.f);
      float x3 = fmaxf(accT[rs][cs][3] + b, 0.f);
      unsigned w01 = cvtpk(x0, x1), w23 = cvtpk(x2, x3);
      int row = rs * 16 + rb;
      ldsT[(row + 0) * LDA + col] = (unsigned short)w01;
      ldsT[(row + 1) * LDA + col] = (unsigned short)(w01 >> 16);
      ldsT[(row + 2) * LDA + col] = (unsigned short)w23;
      ldsT[(row + 3) * LDA + col] = (unsigned short)(w23 >> 16);
    }
  }
}

#define ZERO44(A)                      \
  _Pragma("unroll") for (int a_ = 0; a_ < 4; ++a_) _Pragma("unroll") \
      for (int b_ = 0; b_ < 4; ++b_) A[a_][b_] = (f32x4){0.f, 0.f, 0.f, 0.f};

__global__ __launch_bounds__(256, 2) void fused_k(
    const float* __restrict__ n1, const float* __restrict__ n2,
    const float* __restrict__ eg, const unsigned short* __restrict__ W1t,
    const unsigned short* __restrict__ W2t, const unsigned short* __restrict__ Wet,
    const unsigned short* __restrict__ Ut, const float* __restrict__ b1,
    const float* __restrict__ b2, const float* __restrict__ be,
    const float* __restrict__ bout, const int* __restrict__ ridx,
    const int* __restrict__ tpair, const int* __restrict__ tstart,
    const int* __restrict__ tnr, const int* __restrict__ ntl,
    float* __restrict__ out) {
  // bijective XCD swizzle: same-pair tiles (consecutive) -> same XCD's L2
  int nwg = gridDim.x, orig = blockIdx.x;
  int q = nwg >> 3, rr = nwg & 7, xc = orig & 7, sidx = orig >> 3;
  int tile = (xc < rr ? xc * (q + 1) : rr * (q + 1) + (xc - rr) * q) + sidx;
  if (tile >= ntl[0]) return;

  const int pr = tpair[tile];
  const int t1 = pr / J_TYPES, t2 = pr % J_TYPES;
  const int ts = tstart[tile];
  const int nrows = tnr[tile];
  const int* __restrict__ ridxp = ridx + ts;

  __shared__ unsigned short ldsA[TILE * LDA];
  __shared__ unsigned short ldsT[TILE * LDA];
  __shared__ int srow[TILE];

  const int lane = threadIdx.x & 63;
  const int wave = __builtin_amdgcn_readfirstlane(threadIdx.x >> 6);
  const int r0 = lane & 15;
  const int kg = (lane >> 4) * 8;
  const int rb = (lane >> 4) * 4;

  if (threadIdx.x < TILE)
    srow[threadIdx.x] = (threadIdx.x < nrows) ? ridxp[threadIdx.x] : -1;
  // srow read only in final epilogue (many barriers between)

  f32x4 accT[4][4], accO[4][4];
  float4 s4[16];
  float2 s2[16];

  // ---- prologue: stage path0 (n1)
  stage_issue256(n1, ridxp, nrows, wave, lane, s4);
  stage_write256(s4, ldsA, wave, lane);
  __syncthreads();

  // ---- Y0: gemm1(0)  [+ issue n2 loads]
  stage_issue256(n2, ridxp, nrows, wave, lane, s4);
  ZERO44(accT);
  gemm_full<8, LDA>(ldsA, W1t + (size_t)t1 * 65536, accT, r0, kg, lane, wave);
  __syncthreads();

  // ---- X0: epi(0) -> ldsT ; stage_write(n2) -> ldsA
  epi_full(accT, b1 + t1 * 256, ldsT, r0, rb, wave);
  stage_write256(s4, ldsA, wave, lane);
  __syncthreads();

  // ---- Y1: gemm2(0) + gemm1(1)  [+ issue edge loads]
  ZERO44(accO);
  gemm_full<8, LDA>(ldsT, Ut, accO, r0, kg, lane, wave);
  stage_issue128(eg, ridxp, nrows, wave, lane, s2);
  ZERO44(accT);
  gemm_full<8, LDA>(ldsA, W2t + (size_t)t2 * 65536, accT, r0, kg, lane, wave);
  __syncthreads();

  // ---- X1: epi(1) -> ldsT ; stage_write(edge) -> ldsA
  epi_full(accT, b2 + t2 * 256, ldsT, r0, rb, wave);
  stage_write128(s2, ldsA, wave, lane);
  __syncthreads();

  // ---- Y2: gemm2(1) + gemm1(edge)
  gemm_full<8, LDA>(ldsT, Ut + 65536, accO, r0, kg, lane, wave);
  ZERO44(accT);
  gemm_full<4, LDE>(ldsA, Wet, accT, r0, kg, lane, wave);
  __syncthreads();

  // ---- X2: epi(edge) -> ldsT
  epi_full(accT, be, ldsT, r0, rb, wave);
  __syncthreads();

  // ---- Y3: gemm2(edge)
  gemm_full<8, LDA>(ldsT, Ut + 2 * 65536, accO, r0, kg, lane, wave);

  // ---- epilogue: relu(accO + bout) -> scattered rows
#pragma unroll
  for (int cs = 0; cs < 4; ++cs) {
    int col = wave * 64 + cs * 16 + r0;
    float bo = bout[col];
#pragma unroll
    for (int rs = 0; rs < 4; ++rs)
#pragma unroll
      for (int i = 0; i < 4; ++i) {
        int row = rs * 16 + rb + i;
        if (row < nrows) {
          float v = fmaxf(accO[rs][cs][i] + bo, 0.f);
          out[(size_t)srow[row] * 256 + col] = v;
        }
      }
  }
}

// ---------------- launcher ----------------
extern "C" void kernel_launch(void* const* d_in, const int* in_sizes, int n_in,
                              void* d_out, int out_size, void* d_ws, size_t ws_size,
                              hipStream_t stream) {
  const float* n1   = (const float*)d_in[0];
  const float* n2   = (const float*)d_in[1];
  const float* eg   = (const float*)d_in[2];
  const int*   ty1  = (const int*)d_in[3];
  const int*   ty2  = (const int*)d_in[4];
  const float* W1   = (const float*)d_in[5];
  const float* b1   = (const float*)d_in[6];
  const float* W2   = (const float*)d_in[7];
  const float* b2   = (const float*)d_in[8];
  const float* We   = (const float*)d_in[9];
  const float* be   = (const float*)d_in[10];
  const float* Wout = (const float*)d_in[11];
  const float* bout = (const float*)d_in[12];
  float* out = (float*)d_out;

  const int N = in_sizes[0] / DN;
  const int maxt = (N + TILE - 1) / TILE + PAIRS;

  char* ws = (char*)d_ws;
  size_t off = 0;
  auto take = [&](size_t bytes) -> char* {
    char* p = ws + off;
    off += (bytes + 255) & ~(size_t)255;
    return p;
  };
  int* cnt = (int*)take(PAIRS * 4);
  int* c2  = (int*)take(PAIRS * 4);
  int* ntl = (int*)take(4);
  int* seg = (int*)take((PAIRS + 1) * 4);
  int* tp  = (int*)take((size_t)maxt * 4);
  int* tst = (int*)take((size_t)maxt * 4);
  int* tnr = (int*)take((size_t)maxt * 4);
  int* ridx = (int*)take((size_t)N * 4);
  unsigned short* W1t = (unsigned short*)take((size_t)J_TYPES * 65536 * 2);
  unsigned short* W2t = (unsigned short*)take((size_t)J_TYPES * 65536 * 2);
  unsigned short* Wet = (unsigned short*)take((size_t)DE * DO * 2);
  unsigned short* Ut  = (unsigned short*)take((size_t)3 * 65536 * 2);
  (void)ws_size; (void)n_in; (void)out_size;

  hipMemsetAsync(cnt, 0, (size_t)((char*)seg - (char*)cnt), stream);
  prep_w_k<<<1024, 256, 0, stream>>>(W1, W2, We, Wout, W1t, W2t, Wet, Ut);
  hist_k<<<400, 256, 0, stream>>>(ty1, ty2, cnt, N);
  scan_tiles_k<<<1, 512, 0, stream>>>(cnt, seg, tp, tst, tnr, ntl);
  scatter_k<<<256, 256, 0, stream>>>(ty1, ty2, seg, c2, ridx, N);
  fused_k<<<maxt, 256, 0, stream>>>(n1, n2, eg, W1t, W2t, Wet, Ut, b1, b2, be, bout,
                                    ridx, tp, tst, tnr, ntl, out);
}

// Round 6
// 323.142 us; speedup vs baseline: 2.0315x; 1.0996x over previous
//
#include <hip/hip_runtime.h>

// TypeAwareEdgeUpdate: out = relu(relu(cat[n1@W1[t1]+b1, n2@W2[t2]+b2, e@We+be]) @ Wout + bout)
// Counting-sort rows by (t1,t2) -> 64-row tiles share weights -> fused bf16 MFMA.
// R6: raw barriers (lgkm-only wait, vmcnt floats across phases), explicit 2-deep
// B-weight double-buffer in gemm, s_setprio around MFMA clusters.

#define J_TYPES 17
#define PAIRS   (J_TYPES * J_TYPES)
#define DN      256
#define DE      128
#define DO      256
#define TILE    64
#define LDA     264   // ldsA / ldsT stride (shorts) for 256 cols
#define LDE     136   // ldsA stride for K=128 (edge path)

typedef short bf16x8 __attribute__((ext_vector_type(8)));
typedef float f32x4  __attribute__((ext_vector_type(4)));

// LDS-only barrier: wait LDS ops, let VMEM (prefetch) stay in flight across it.
#define BAR() asm volatile("s_waitcnt lgkmcnt(0)\n\ts_barrier" ::: "memory")

__device__ __forceinline__ unsigned short f2bf(float x) {
  unsigned u = __float_as_uint(x);
  return (unsigned short)((u + 0x7fffu + ((u >> 16) & 1u)) >> 16);  // RNE
}

__device__ __forceinline__ unsigned cvtpk(float lo, float hi) {
  unsigned r;
  asm("v_cvt_pk_bf16_f32 %0, %1, %2" : "=v"(r) : "v"(lo), "v"(hi));
  return r;  // lo16 = bf16(lo), hi16 = bf16(hi), RNE
}

// ---------------- weight prep: bf16, fragment-native layout ----------------
// Layout per matrix: [colt][k32][lane][i] (shorts), element (col,k):
//   col = colt*16 + (lane&15), k = k32*32 + (lane>>4)*8 + i
// One (colt,k32) tile = 512 shorts = 1KB; a wave's B-frag load = tile + lane*8.
__global__ void prep_w_k(const float* __restrict__ W1, const float* __restrict__ W2,
                         const float* __restrict__ We, const float* __restrict__ Wout,
                         unsigned short* __restrict__ W1t, unsigned short* __restrict__ W2t,
                         unsigned short* __restrict__ Wet, unsigned short* __restrict__ Ut) {
  const int SZW = J_TYPES * 65536;
  const int total = SZW * 2 + DE * DO + 3 * 65536;
  for (int o = blockIdx.x * blockDim.x + threadIdx.x; o < total;
       o += gridDim.x * blockDim.x) {
    int idx = o;
    if (idx < SZW) {                       // W1 frag-native, K=256
      int j = idx >> 16, r = idx & 65535;
      int i = r & 7, lane = (r >> 3) & 63, t = r >> 9;
      int k32 = t & 7, colt = t >> 3;
      int col = colt * 16 + (lane & 15);
      int k = k32 * 32 + ((lane >> 4) << 3) + i;
      W1t[idx] = f2bf(W1[((size_t)j * 256 + k) * 256 + col]);
    } else if ((idx -= SZW) < SZW) {       // W2
      int j = idx >> 16, r = idx & 65535;
      int i = r & 7, lane = (r >> 3) & 63, t = r >> 9;
      int k32 = t & 7, colt = t >> 3;
      int col = colt * 16 + (lane & 15);
      int k = k32 * 32 + ((lane >> 4) << 3) + i;
      W2t[idx] = f2bf(W2[((size_t)j * 256 + k) * 256 + col]);
    } else if ((idx -= SZW) < DE * DO) {   // We, K=128 (4 k32-tiles per colt)
      int r = idx;
      int i = r & 7, lane = (r >> 3) & 63, t = r >> 9;
      int k32 = t & 3, colt = t >> 2;
      int col = colt * 16 + (lane & 15);
      int k = k32 * 32 + ((lane >> 4) << 3) + i;
      Wet[idx] = f2bf(We[(size_t)k * 256 + col]);
    } else {                               // Wout (3 stacked K=256 matrices)
      idx -= DE * DO;
      int p = idx >> 16, r = idx & 65535;
      int i = r & 7, lane = (r >> 3) & 63, t = r >> 9;
      int k32 = t & 7, colt = t >> 3;
      int col = colt * 16 + (lane & 15);
      int k = k32 * 32 + ((lane >> 4) << 3) + i;
      Ut[idx] = f2bf(Wout[((size_t)p * 256 + k) * 256 + col]);
    }
  }
}

// ---------------- counting sort by pair ----------------
__global__ void hist_k(const int* __restrict__ ty1, const int* __restrict__ ty2,
                       int* __restrict__ cnt, int N) {
  __shared__ int h[PAIRS];
  for (int i = threadIdx.x; i < PAIRS; i += blockDim.x) h[i] = 0;
  __syncthreads();
  for (int i = blockIdx.x * blockDim.x + threadIdx.x; i < N;
       i += gridDim.x * blockDim.x)
    atomicAdd(&h[ty1[i] * J_TYPES + ty2[i]], 1);
  __syncthreads();
  for (int i = threadIdx.x; i < PAIRS; i += blockDim.x) {
    int v = h[i];
    if (v) atomicAdd(&cnt[i], v);
  }
}

__global__ void scan_tiles_k(const int* __restrict__ cnt, int* __restrict__ seg,
                             int* __restrict__ tpair, int* __restrict__ tstart,
                             int* __restrict__ tnr, int* __restrict__ ntl) {
  __shared__ int s1[512], s2[512];
  int t = threadIdx.x;                               // 512 threads
  int c  = (t < PAIRS) ? cnt[t] : 0;
  int nt = (c + TILE - 1) / TILE;
  s1[t] = c; s2[t] = nt;
  __syncthreads();
  for (int o = 1; o < 512; o <<= 1) {                // Hillis-Steele inclusive
    int v1 = (t >= o) ? s1[t - o] : 0;
    int v2 = (t >= o) ? s2[t - o] : 0;
    __syncthreads();
    s1[t] += v1; s2[t] += v2;
    __syncthreads();
  }
  if (t < PAIRS) {
    int segstart = s1[t] - c;
    int tbase    = s2[t] - nt;
    seg[t] = segstart;
    for (int i = 0; i < nt; ++i) {
      tpair[tbase + i]  = t;
      tstart[tbase + i] = segstart + i * TILE;
      int rem = c - i * TILE;
      tnr[tbase + i] = rem < TILE ? rem : TILE;
    }
  }
  if (t == 511) ntl[0] = s2[511];
}

// block-aggregated scatter: one global atomic per (block,pair)
__global__ void scatter_k(const int* __restrict__ ty1, const int* __restrict__ ty2,
                          const int* __restrict__ seg, int* __restrict__ c2,
                          int* __restrict__ ridx, int N) {
  __shared__ int lh[PAIRS], lb[PAIRS];
  int chunk = (N + gridDim.x - 1) / gridDim.x;
  int lo = blockIdx.x * chunk;
  int hi = lo + chunk; if (hi > N) hi = N;
  for (int i = threadIdx.x; i < PAIRS; i += blockDim.x) lh[i] = 0;
  __syncthreads();
  for (int i = lo + threadIdx.x; i < hi; i += blockDim.x)
    atomicAdd(&lh[ty1[i] * J_TYPES + ty2[i]], 1);
  __syncthreads();
  for (int i = threadIdx.x; i < PAIRS; i += blockDim.x) {
    int v = lh[i];
    lb[i] = v ? atomicAdd(&c2[i], v) : 0;
    lh[i] = 0;
  }
  __syncthreads();
  for (int i = lo + threadIdx.x; i < hi; i += blockDim.x) {
    int p = ty1[i] * J_TYPES + ty2[i];
    int pos = seg[p] + lb[p] + atomicAdd(&lh[p], 1);
    ridx[pos] = i;
  }
}

// ---------------- fused tile kernel ----------------
// 4 waves/block, wave w owns cols [w*64, w*64+64) of tmp AND of out.

__device__ __forceinline__ void stage_issue256(const float* __restrict__ src,
                                               const int* __restrict__ ridxp, int nrows,
                                               int wave, int lane, float4 f[16]) {
#pragma unroll
  for (int j = 0; j < 16; ++j) {
    int r = wave + 4 * j;
    int rc = r < nrows ? r : nrows - 1;          // uniform clamp
    int sr = ridxp[rc];                          // scalar load
    f[j] = reinterpret_cast<const float4*>(src + (size_t)sr * DN)[lane];
  }
}

__device__ __forceinline__ void stage_write256(const float4 f[16],
                                               unsigned short* lds, int wave, int lane) {
#pragma unroll
  for (int j = 0; j < 16; ++j) {
    int r = wave + 4 * j;
    unsigned lo = cvtpk(f[j].x, f[j].y), hi = cvtpk(f[j].z, f[j].w);
    *reinterpret_cast<uint2*>(lds + r * LDA + lane * 4) = make_uint2(lo, hi);
  }
}

__device__ __forceinline__ void stage_issue128(const float* __restrict__ src,
                                               const int* __restrict__ ridxp, int nrows,
                                               int wave, int lane, float2 f[16]) {
#pragma unroll
  for (int j = 0; j < 16; ++j) {
    int r = wave + 4 * j;
    int rc = r < nrows ? r : nrows - 1;
    int sr = ridxp[rc];
    f[j] = reinterpret_cast<const float2*>(src + (size_t)sr * DE)[lane];
  }
}

__device__ __forceinline__ void stage_write128(const float2 f[16],
                                               unsigned short* lds, int wave, int lane) {
#pragma unroll
  for (int j = 0; j < 16; ++j) {
    int r = wave + 4 * j;
    *reinterpret_cast<unsigned*>(lds + r * LDE + lane * 2) = cvtpk(f[j].x, f[j].y);
  }
}

// Full-width gemm: wave computes 64 rows x 64 cols over K = NK*32.
// Explicit 2-deep double-buffer on B-frags: next k32's 4 weight loads are issued
// (in IR order) before the current k32's MFMA cluster.
template <int NK, int LD>
__device__ __forceinline__ void gemm_full(const unsigned short* lds,
                                          const unsigned short* __restrict__ Wbase,
                                          f32x4 acc[4][4], int r0, int kg, int lane,
                                          int wave) {
  const unsigned short* w = Wbase + ((size_t)(wave * 4) * NK) * 512 + lane * 8;
  bf16x8 bf[2][4];
#pragma unroll
  for (int cs = 0; cs < 4; ++cs)
    bf[0][cs] = *reinterpret_cast<const bf16x8*>(w + ((size_t)cs * NK) * 512);
#pragma unroll
  for (int k32 = 0; k32 < NK; ++k32) {
    const int cur = k32 & 1, nxt = cur ^ 1;     // compile-time under full unroll
    if (k32 + 1 < NK) {
#pragma unroll
      for (int cs = 0; cs < 4; ++cs)
        bf[nxt][cs] =
            *reinterpret_cast<const bf16x8*>(w + ((size_t)cs * NK + k32 + 1) * 512);
    }
    bf16x8 af[4];
#pragma unroll
    for (int rs = 0; rs < 4; ++rs)
      af[rs] = *reinterpret_cast<const bf16x8*>(lds + (rs * 16 + r0) * LD + k32 * 32 + kg);
    __builtin_amdgcn_s_setprio(1);
#pragma unroll
    for (int rs = 0; rs < 4; ++rs)
#pragma unroll
      for (int cs = 0; cs < 4; ++cs)
        acc[rs][cs] = __builtin_amdgcn_mfma_f32_16x16x32_bf16(af[rs], bf[cur][cs],
                                                              acc[rs][cs], 0, 0, 0);
    __builtin_amdgcn_s_setprio(0);
  }
}

// epi: relu(accT + bias) -> bf16 -> ldsT (full 256-col tile, this wave's 64 cols)
__device__ __forceinline__ void epi_full(f32x4 accT[4][4], const float* __restrict__ bias,
                                         unsigned short* ldsT, int r0, int rb, int wave) {
#pragma unroll
  for (int cs = 0; cs < 4; ++cs) {
    int col = wave * 64 + cs * 16 + r0;
    float b = bias[col];
#pragma unroll
    for (int rs = 0; rs < 4; ++rs) {
      float x0 = fmaxf(accT[rs][cs][0] + b, 0.f);
      float x1 = fmaxf(accT[rs][cs][1] + b, 0.f);
      float x2 = fmaxf(accT[rs][cs][2] + b, 0.f);
      float x3 = fmaxf(accT[rs][cs][3] + b, 0.f);
      unsigned w01 = cvtpk(x0, x1), w23 = cvtpk(x2, x3);
      int row = rs * 16 + rb;
      ldsT[(row + 0) * LDA + col] = (unsigned short)w01;
      ldsT[(row + 1) * LDA + col] = (unsigned short)(w01 >> 16);
      ldsT[(row + 2) * LDA + col] = (unsigned short)w23;
      ldsT[(row + 3) * LDA + col] = (unsigned short)(w23 >> 16);
    }
  }
}

#define ZERO44(A)                      \
  _Pragma("unroll") for (int a_ = 0; a_ < 4; ++a_) _Pragma("unroll") \
      for (int b_ = 0; b_ < 4; ++b_) A[a_][b_] = (f32x4){0.f, 0.f, 0.f, 0.f};

__global__ __launch_bounds__(256, 2) void fused_k(
    const float* __restrict__ n1, const float* __restrict__ n2,
    const float* __restrict__ eg, const unsigned short* __restrict__ W1t,
    const unsigned short* __restrict__ W2t, const unsigned short* __restrict__ Wet,
    const unsigned short* __restrict__ Ut, const float* __restrict__ b1,
    const float* __restrict__ b2, const float* __restrict__ be,
    const float* __restrict__ bout, const int* __restrict__ ridx,
    const int* __restrict__ tpair, const int* __restrict__ tstart,
    const int* __restrict__ tnr, const int* __restrict__ ntl,
    float* __restrict__ out) {
  // bijective XCD swizzle: same-pair tiles (consecutive) -> same XCD's L2
  int nwg = gridDim.x, orig = blockIdx.x;
  int q = nwg >> 3, rr = nwg & 7, xc = orig & 7, sidx = orig >> 3;
  int tile = (xc < rr ? xc * (q + 1) : rr * (q + 1) + (xc - rr) * q) + sidx;
  if (tile >= ntl[0]) return;

  const int pr = tpair[tile];
  const int t1 = pr / J_TYPES, t2 = pr % J_TYPES;
  const int ts = tstart[tile];
  const int nrows = tnr[tile];
  const int* __restrict__ ridxp = ridx + ts;

  __shared__ unsigned short ldsA[TILE * LDA];
  __shared__ unsigned short ldsT[TILE * LDA];
  __shared__ int srow[TILE];

  const int lane = threadIdx.x & 63;
  const int wave = __builtin_amdgcn_readfirstlane(threadIdx.x >> 6);
  const int r0 = lane & 15;
  const int kg = (lane >> 4) * 8;
  const int rb = (lane >> 4) * 4;

  if (threadIdx.x < TILE)
    srow[threadIdx.x] = (threadIdx.x < nrows) ? ridxp[threadIdx.x] : -1;
  // srow read only in final epilogue (barriers between)

  f32x4 accT[4][4], accO[4][4];
  float4 s4[16];
  float2 s2[16];

  // ---- prologue: stage path0 (n1)
  stage_issue256(n1, ridxp, nrows, wave, lane, s4);
  stage_write256(s4, ldsA, wave, lane);
  BAR();

  // ---- Y0: issue n2 prefetch; gemm1(0)
  stage_issue256(n2, ridxp, nrows, wave, lane, s4);
  ZERO44(accT);
  gemm_full<8, LDA>(ldsA, W1t + (size_t)t1 * 65536, accT, r0, kg, lane, wave);
  BAR();

  // ---- X0: epi(0) -> ldsT ; stage_write(n2) -> ldsA
  epi_full(accT, b1 + t1 * 256, ldsT, r0, rb, wave);
  stage_write256(s4, ldsA, wave, lane);
  BAR();

  // ---- Y1: issue edge prefetch; gemm2(0) + gemm1(1)
  stage_issue128(eg, ridxp, nrows, wave, lane, s2);
  ZERO44(accO);
  gemm_full<8, LDA>(ldsT, Ut, accO, r0, kg, lane, wave);
  ZERO44(accT);
  gemm_full<8, LDA>(ldsA, W2t + (size_t)t2 * 65536, accT, r0, kg, lane, wave);
  BAR();

  // ---- X1: epi(1) -> ldsT ; stage_write(edge) -> ldsA
  epi_full(accT, b2 + t2 * 256, ldsT, r0, rb, wave);
  stage_write128(s2, ldsA, wave, lane);
  BAR();

  // ---- Y2: gemm2(1) + gemm1(edge)
  gemm_full<8, LDA>(ldsT, Ut + 65536, accO, r0, kg, lane, wave);
  ZERO44(accT);
  gemm_full<4, LDE>(ldsA, Wet, accT, r0, kg, lane, wave);
  BAR();

  // ---- X2: epi(edge) -> ldsT
  epi_full(accT, be, ldsT, r0, rb, wave);
  BAR();

  // ---- Y3: gemm2(edge)
  gemm_full<8, LDA>(ldsT, Ut + 2 * 65536, accO, r0, kg, lane, wave);

  // ---- epilogue: relu(accO + bout) -> scattered rows
#pragma unroll
  for (int cs = 0; cs < 4; ++cs) {
    int col = wave * 64 + cs * 16 + r0;
    float bo = bout[col];
#pragma unroll
    for (int rs = 0; rs < 4; ++rs)
#pragma unroll
      for (int i = 0; i < 4; ++i) {
        int row = rs * 16 + rb + i;
        if (row < nrows) {
          float v = fmaxf(accO[rs][cs][i] + bo, 0.f);
          out[(size_t)srow[row] * 256 + col] = v;
        }
      }
  }
}

// ---------------- launcher ----------------
extern "C" void kernel_launch(void* const* d_in, const int* in_sizes, int n_in,
                              void* d_out, int out_size, void* d_ws, size_t ws_size,
                              hipStream_t stream) {
  const float* n1   = (const float*)d_in[0];
  const float* n2   = (const float*)d_in[1];
  const float* eg   = (const float*)d_in[2];
  const int*   ty1  = (const int*)d_in[3];
  const int*   ty2  = (const int*)d_in[4];
  const float* W1   = (const float*)d_in[5];
  const float* b1   = (const float*)d_in[6];
  const float* W2   = (const float*)d_in[7];
  const float* b2   = (const float*)d_in[8];
  const float* We   = (const float*)d_in[9];
  const float* be   = (const float*)d_in[10];
  const float* Wout = (const float*)d_in[11];
  const float* bout = (const float*)d_in[12];
  float* out = (float*)d_out;

  const int N = in_sizes[0] / DN;
  const int maxt = (N + TILE - 1) / TILE + PAIRS;

  char* ws = (char*)d_ws;
  size_t off = 0;
  auto take = [&](size_t bytes) -> char* {
    char* p = ws + off;
    off += (bytes + 255) & ~(size_t)255;
    return p;
  };
  int* cnt = (int*)take(PAIRS * 4);
  int* c2  = (int*)take(PAIRS * 4);
  int* ntl = (int*)take(4);
  int* seg = (int*)take((PAIRS + 1) * 4);
  int* tp  = (int*)take((size_t)maxt * 4);
  int* tst = (int*)take((size_t)maxt * 4);
  int* tnr = (int*)take((size_t)maxt * 4);
  int* ridx = (int*)take((size_t)N * 4);
  unsigned short* W1t = (unsigned short*)take((size_t)J_TYPES * 65536 * 2);
  unsigned short* W2t = (unsigned short*)take((size_t)J_TYPES * 65536 * 2);
  unsigned short* Wet = (unsigned short*)take((size_t)DE * DO * 2);
  unsigned short* Ut  = (unsigned short*)take((size_t)3 * 65536 * 2);
  (void)ws_size; (void)n_in; (void)out_size;

  hipMemsetAsync(cnt, 0, (size_t)((char*)seg - (char*)cnt), stream);
  prep_w_k<<<1024, 256, 0, stream>>>(W1, W2, We, Wout, W1t, W2t, Wet, Ut);
  hist_k<<<400, 256, 0, stream>>>(ty1, ty2, cnt, N);
  scan_tiles_k<<<1, 512, 0, stream>>>(cnt, seg, tp, tst, tnr, ntl);
  scatter_k<<<256, 256, 0, stream>>>(ty1, ty2, seg, c2, ridx, N);
  fused_k<<<maxt, 256, 0, stream>>>(n1, n2, eg, W1t, W2t, Wet, Ut, b1, b2, be, bout,
                                    ridx, tp, tst, tnr, ntl, out);
}

// Round 7
// 289.810 us; speedup vs baseline: 2.2651x; 1.1150x over previous
//
#include <hip/hip_runtime.h>

// TypeAwareEdgeUpdate: out = relu(relu(cat[n1@W1[t1]+b1, n2@W2[t2]+b2, e@We+be]) @ Wout + bout)
// Counting-sort rows by (t1,t2) -> 64-row tiles share weights -> fused bf16 MFMA.
// R7: 8 waves x 32 cols (512 thr), VGPR<=128 => 2 blocks/CU = 4 waves/SIMD (2x TLP),
//     per-wave k-stagger, 2-deep B dbuf, lgkm-only barriers, setprio.

#define J_TYPES 17
#define PAIRS   (J_TYPES * J_TYPES)
#define DN      256
#define DE      128
#define DO      256
#define TILE    64
#define LDA     264   // ldsA / ldsT stride (shorts) for 256 cols
#define LDE     136   // ldsA stride for K=128 (edge path)

typedef short bf16x8 __attribute__((ext_vector_type(8)));
typedef float f32x4  __attribute__((ext_vector_type(4)));

// LDS-only barrier: wait LDS ops, let VMEM stay in flight across it.
#define BAR() asm volatile("s_waitcnt lgkmcnt(0)\n\ts_barrier" ::: "memory")

__device__ __forceinline__ unsigned short f2bf(float x) {
  unsigned u = __float_as_uint(x);
  return (unsigned short)((u + 0x7fffu + ((u >> 16) & 1u)) >> 16);  // RNE
}

__device__ __forceinline__ unsigned cvtpk(float lo, float hi) {
  unsigned r;
  asm("v_cvt_pk_bf16_f32 %0, %1, %2" : "=v"(r) : "v"(lo), "v"(hi));
  return r;  // lo16 = bf16(lo), hi16 = bf16(hi), RNE
}

// ---------------- weight prep: bf16, fragment-native layout ----------------
// Layout per matrix: [colt][k32][lane][i] (shorts), element (col,k):
//   col = colt*16 + (lane&15), k = k32*32 + (lane>>4)*8 + i
// One (colt,k32) tile = 512 shorts = 1KB; a wave's B-frag load = tile + lane*8.
__global__ void prep_w_k(const float* __restrict__ W1, const float* __restrict__ W2,
                         const float* __restrict__ We, const float* __restrict__ Wout,
                         unsigned short* __restrict__ W1t, unsigned short* __restrict__ W2t,
                         unsigned short* __restrict__ Wet, unsigned short* __restrict__ Ut) {
  const int SZW = J_TYPES * 65536;
  const int total = SZW * 2 + DE * DO + 3 * 65536;
  for (int o = blockIdx.x * blockDim.x + threadIdx.x; o < total;
       o += gridDim.x * blockDim.x) {
    int idx = o;
    if (idx < SZW) {                       // W1 frag-native, K=256
      int j = idx >> 16, r = idx & 65535;
      int i = r & 7, lane = (r >> 3) & 63, t = r >> 9;
      int k32 = t & 7, colt = t >> 3;
      int col = colt * 16 + (lane & 15);
      int k = k32 * 32 + ((lane >> 4) << 3) + i;
      W1t[idx] = f2bf(W1[((size_t)j * 256 + k) * 256 + col]);
    } else if ((idx -= SZW) < SZW) {       // W2
      int j = idx >> 16, r = idx & 65535;
      int i = r & 7, lane = (r >> 3) & 63, t = r >> 9;
      int k32 = t & 7, colt = t >> 3;
      int col = colt * 16 + (lane & 15);
      int k = k32 * 32 + ((lane >> 4) << 3) + i;
      W2t[idx] = f2bf(W2[((size_t)j * 256 + k) * 256 + col]);
    } else if ((idx -= SZW) < DE * DO) {   // We, K=128 (4 k32-tiles per colt)
      int r = idx;
      int i = r & 7, lane = (r >> 3) & 63, t = r >> 9;
      int k32 = t & 3, colt = t >> 2;
      int col = colt * 16 + (lane & 15);
      int k = k32 * 32 + ((lane >> 4) << 3) + i;
      Wet[idx] = f2bf(We[(size_t)k * 256 + col]);
    } else {                               // Wout (3 stacked K=256 matrices)
      idx -= DE * DO;
      int p = idx >> 16, r = idx & 65535;
      int i = r & 7, lane = (r >> 3) & 63, t = r >> 9;
      int k32 = t & 7, colt = t >> 3;
      int col = colt * 16 + (lane & 15);
      int k = k32 * 32 + ((lane >> 4) << 3) + i;
      Ut[idx] = f2bf(Wout[((size_t)p * 256 + k) * 256 + col]);
    }
  }
}

// ---------------- counting sort by pair ----------------
__global__ void hist_k(const int* __restrict__ ty1, const int* __restrict__ ty2,
                       int* __restrict__ cnt, int N) {
  __shared__ int h[PAIRS];
  for (int i = threadIdx.x; i < PAIRS; i += blockDim.x) h[i] = 0;
  __syncthreads();
  for (int i = blockIdx.x * blockDim.x + threadIdx.x; i < N;
       i += gridDim.x * blockDim.x)
    atomicAdd(&h[ty1[i] * J_TYPES + ty2[i]], 1);
  __syncthreads();
  for (int i = threadIdx.x; i < PAIRS; i += blockDim.x) {
    int v = h[i];
    if (v) atomicAdd(&cnt[i], v);
  }
}

__global__ void scan_tiles_k(const int* __restrict__ cnt, int* __restrict__ seg,
                             int* __restrict__ tpair, int* __restrict__ tstart,
                             int* __restrict__ tnr, int* __restrict__ ntl) {
  __shared__ int s1[512], s2[512];
  int t = threadIdx.x;                               // 512 threads
  int c  = (t < PAIRS) ? cnt[t] : 0;
  int nt = (c + TILE - 1) / TILE;
  s1[t] = c; s2[t] = nt;
  __syncthreads();
  for (int o = 1; o < 512; o <<= 1) {                // Hillis-Steele inclusive
    int v1 = (t >= o) ? s1[t - o] : 0;
    int v2 = (t >= o) ? s2[t - o] : 0;
    __syncthreads();
    s1[t] += v1; s2[t] += v2;
    __syncthreads();
  }
  if (t < PAIRS) {
    int segstart = s1[t] - c;
    int tbase    = s2[t] - nt;
    seg[t] = segstart;
    for (int i = 0; i < nt; ++i) {
      tpair[tbase + i]  = t;
      tstart[tbase + i] = segstart + i * TILE;
      int rem = c - i * TILE;
      tnr[tbase + i] = rem < TILE ? rem : TILE;
    }
  }
  if (t == 511) ntl[0] = s2[511];
}

// block-aggregated scatter: one global atomic per (block,pair)
__global__ void scatter_k(const int* __restrict__ ty1, const int* __restrict__ ty2,
                          const int* __restrict__ seg, int* __restrict__ c2,
                          int* __restrict__ ridx, int N) {
  __shared__ int lh[PAIRS], lb[PAIRS];
  int chunk = (N + gridDim.x - 1) / gridDim.x;
  int lo = blockIdx.x * chunk;
  int hi = lo + chunk; if (hi > N) hi = N;
  for (int i = threadIdx.x; i < PAIRS; i += blockDim.x) lh[i] = 0;
  __syncthreads();
  for (int i = lo + threadIdx.x; i < hi; i += blockDim.x)
    atomicAdd(&lh[ty1[i] * J_TYPES + ty2[i]], 1);
  __syncthreads();
  for (int i = threadIdx.x; i < PAIRS; i += blockDim.x) {
    int v = lh[i];
    lb[i] = v ? atomicAdd(&c2[i], v) : 0;
    lh[i] = 0;
  }
  __syncthreads();
  for (int i = lo + threadIdx.x; i < hi; i += blockDim.x) {
    int p = ty1[i] * J_TYPES + ty2[i];
    int pos = seg[p] + lb[p] + atomicAdd(&lh[p], 1);
    ridx[pos] = i;
  }
}

// ---------------- fused tile kernel ----------------
// 8 waves/block (512 thr), wave w owns cols [w*32, w*32+32) of tmp AND of out.
// A-frag: lane l -> row (l&15)+16rs, k=(l>>4)*8..+7 (b128 from LDS)
// B-frag: contiguous 1KB wave load from frag-native weights
// D-frag: col = l&15, row = (l>>4)*4 + reg

__device__ __forceinline__ void stage256(const float* __restrict__ src,
                                         const int* __restrict__ ridxp, int nrows,
                                         unsigned short* lds, int wave, int lane) {
  float4 f[8];
#pragma unroll
  for (int j = 0; j < 8; ++j) {
    int r = wave + 8 * j;
    int rc = r < nrows ? r : nrows - 1;          // uniform clamp
    int sr = ridxp[rc];                          // scalar load
    f[j] = reinterpret_cast<const float4*>(src + (size_t)sr * DN)[lane];
  }
#pragma unroll
  for (int j = 0; j < 8; ++j) {
    int r = wave + 8 * j;
    unsigned lo = cvtpk(f[j].x, f[j].y), hi = cvtpk(f[j].z, f[j].w);
    *reinterpret_cast<uint2*>(lds + r * LDA + lane * 4) = make_uint2(lo, hi);
  }
}

__device__ __forceinline__ void stage128(const float* __restrict__ src,
                                         const int* __restrict__ ridxp, int nrows,
                                         unsigned short* lds, int wave, int lane) {
  float2 f[8];
#pragma unroll
  for (int j = 0; j < 8; ++j) {
    int r = wave + 8 * j;
    int rc = r < nrows ? r : nrows - 1;
    int sr = ridxp[rc];
    f[j] = reinterpret_cast<const float2*>(src + (size_t)sr * DE)[lane];
  }
#pragma unroll
  for (int j = 0; j < 8; ++j) {
    int r = wave + 8 * j;
    *reinterpret_cast<unsigned*>(lds + r * LDE + lane * 2) = cvtpk(f[j].x, f[j].y);
  }
}

// Wave computes 64 rows x 32 cols over K = NK*32, with per-wave k-stagger:
// wave w starts at k32=(w & NK-1) so co-resident waves hit different pipe stages.
// 2-deep B double-buffer (static indices under full unroll).
template <int NK, int LD>
__device__ __forceinline__ void gemm32(const unsigned short* lds,
                                       const unsigned short* __restrict__ Wbase,
                                       f32x4 acc[4][2], int r0, int kg, int lane,
                                       int wave) {
  const unsigned short* w = Wbase + ((size_t)(wave * 2) * NK) * 512 + lane * 8;
  const int kw = wave & (NK - 1);
  bf16x8 bf[2][2];
#pragma unroll
  for (int cs = 0; cs < 2; ++cs)
    bf[0][cs] = *reinterpret_cast<const bf16x8*>(w + ((size_t)cs * NK + kw) * 512);
#pragma unroll
  for (int i = 0; i < NK; ++i) {
    const int cur = i & 1, nxt = cur ^ 1;        // compile-time under full unroll
    const int kk = (i + wave) & (NK - 1);        // runtime-uniform, addr-only
    if (i + 1 < NK) {
      const int kk1 = (i + 1 + wave) & (NK - 1);
#pragma unroll
      for (int cs = 0; cs < 2; ++cs)
        bf[nxt][cs] =
            *reinterpret_cast<const bf16x8*>(w + ((size_t)cs * NK + kk1) * 512);
    }
    bf16x8 af[4];
#pragma unroll
    for (int rs = 0; rs < 4; ++rs)
      af[rs] = *reinterpret_cast<const bf16x8*>(lds + (rs * 16 + r0) * LD + kk * 32 + kg);
    __builtin_amdgcn_s_setprio(1);
#pragma unroll
    for (int rs = 0; rs < 4; ++rs)
#pragma unroll
      for (int cs = 0; cs < 2; ++cs)
        acc[rs][cs] = __builtin_amdgcn_mfma_f32_16x16x32_bf16(af[rs], bf[cur][cs],
                                                              acc[rs][cs], 0, 0, 0);
    __builtin_amdgcn_s_setprio(0);
  }
}

// epi: relu(accT + bias) -> bf16 -> ldsT (this wave's 32 cols)
__device__ __forceinline__ void epi32(f32x4 accT[4][2], const float* __restrict__ bias,
                                      unsigned short* ldsT, int r0, int rb, int wave) {
#pragma unroll
  for (int cs = 0; cs < 2; ++cs) {
    int col = wave * 32 + cs * 16 + r0;
    float b = bias[col];
#pragma unroll
    for (int rs = 0; rs < 4; ++rs) {
      float x0 = fmaxf(accT[rs][cs][0] + b, 0.f);
      float x1 = fmaxf(accT[rs][cs][1] + b, 0.f);
      float x2 = fmaxf(accT[rs][cs][2] + b, 0.f);
      float x3 = fmaxf(accT[rs][cs][3] + b, 0.f);
      unsigned w01 = cvtpk(x0, x1), w23 = cvtpk(x2, x3);
      int row = rs * 16 + rb;
      ldsT[(row + 0) * LDA + col] = (unsigned short)w01;
      ldsT[(row + 1) * LDA + col] = (unsigned short)(w01 >> 16);
      ldsT[(row + 2) * LDA + col] = (unsigned short)w23;
      ldsT[(row + 3) * LDA + col] = (unsigned short)(w23 >> 16);
    }
  }
}

#define ZERO42(A)                                                        \
  _Pragma("unroll") for (int a_ = 0; a_ < 4; ++a_) _Pragma("unroll")     \
      for (int b_ = 0; b_ < 2; ++b_) A[a_][b_] = (f32x4){0.f, 0.f, 0.f, 0.f};

__global__ __launch_bounds__(512, 4) void fused_k(
    const float* __restrict__ n1, const float* __restrict__ n2,
    const float* __restrict__ eg, const unsigned short* __restrict__ W1t,
    const unsigned short* __restrict__ W2t, const unsigned short* __restrict__ Wet,
    const unsigned short* __restrict__ Ut, const float* __restrict__ b1,
    const float* __restrict__ b2, const float* __restrict__ be,
    const float* __restrict__ bout, const int* __restrict__ ridx,
    const int* __restrict__ tpair, const int* __restrict__ tstart,
    const int* __restrict__ tnr, const int* __restrict__ ntl,
    float* __restrict__ out) {
  // bijective XCD swizzle: same-pair tiles (consecutive) -> same XCD's L2
  int nwg = gridDim.x, orig = blockIdx.x;
  int q = nwg >> 3, rr = nwg & 7, xc = orig & 7, sidx = orig >> 3;
  int tile = (xc < rr ? xc * (q + 1) : rr * (q + 1) + (xc - rr) * q) + sidx;
  if (tile >= ntl[0]) return;

  const int pr = tpair[tile];
  const int t1 = pr / J_TYPES, t2 = pr % J_TYPES;
  const int ts = tstart[tile];
  const int nrows = tnr[tile];
  const int* __restrict__ ridxp = ridx + ts;

  __shared__ unsigned short ldsA[TILE * LDA];
  __shared__ unsigned short ldsT[TILE * LDA];
  __shared__ int srow[TILE];

  const int lane = threadIdx.x & 63;
  const int wave = __builtin_amdgcn_readfirstlane(threadIdx.x >> 6);
  const int r0 = lane & 15;
  const int kg = (lane >> 4) * 8;
  const int rb = (lane >> 4) * 4;

  if (threadIdx.x < TILE)
    srow[threadIdx.x] = (threadIdx.x < nrows) ? ridxp[threadIdx.x] : -1;
  // srow read only in final epilogue (barriers between)

  f32x4 accT[4][2], accO[4][2];

  // ---- P: stage n1
  stage256(n1, ridxp, nrows, ldsA, wave, lane);
  BAR();

  // ---- Y0: gemm1(n1)
  ZERO42(accT);
  gemm32<8, LDA>(ldsA, W1t + (size_t)t1 * 65536, accT, r0, kg, lane, wave);
  BAR();

  // ---- X0: epi(0) -> ldsT ; stage n2 -> ldsA
  epi32(accT, b1 + t1 * 256, ldsT, r0, rb, wave);
  stage256(n2, ridxp, nrows, ldsA, wave, lane);
  BAR();

  // ---- Y1: gemm2(0) + gemm1(n2)
  ZERO42(accO);
  gemm32<8, LDA>(ldsT, Ut, accO, r0, kg, lane, wave);
  ZERO42(accT);
  gemm32<8, LDA>(ldsA, W2t + (size_t)t2 * 65536, accT, r0, kg, lane, wave);
  BAR();

  // ---- X1: epi(1) -> ldsT ; stage edge -> ldsA
  epi32(accT, b2 + t2 * 256, ldsT, r0, rb, wave);
  stage128(eg, ridxp, nrows, ldsA, wave, lane);
  BAR();

  // ---- Y2: gemm2(1) + gemm1(edge)
  gemm32<8, LDA>(ldsT, Ut + 65536, accO, r0, kg, lane, wave);
  ZERO42(accT);
  gemm32<4, LDE>(ldsA, Wet, accT, r0, kg, lane, wave);
  BAR();

  // ---- X2: epi(edge) -> ldsT
  epi32(accT, be, ldsT, r0, rb, wave);
  BAR();

  // ---- Y3: gemm2(edge)
  gemm32<8, LDA>(ldsT, Ut + 2 * 65536, accO, r0, kg, lane, wave);

  // ---- epilogue: relu(accO + bout) -> scattered rows
#pragma unroll
  for (int cs = 0; cs < 2; ++cs) {
    int col = wave * 32 + cs * 16 + r0;
    float bo = bout[col];
#pragma unroll
    for (int rs = 0; rs < 4; ++rs)
#pragma unroll
      for (int i = 0; i < 4; ++i) {
        int row = rs * 16 + rb + i;
        if (row < nrows) {
          float v = fmaxf(accO[rs][cs][i] + bo, 0.f);
          out[(size_t)srow[row] * 256 + col] = v;
        }
      }
  }
}

// ---------------- launcher ----------------
extern "C" void kernel_launch(void* const* d_in, const int* in_sizes, int n_in,
                              void* d_out, int out_size, void* d_ws, size_t ws_size,
                              hipStream_t stream) {
  const float* n1   = (const float*)d_in[0];
  const float* n2   = (const float*)d_in[1];
  const float* eg   = (const float*)d_in[2];
  const int*   ty1  = (const int*)d_in[3];
  const int*   ty2  = (const int*)d_in[4];
  const float* W1   = (const float*)d_in[5];
  const float* b1   = (const float*)d_in[6];
  const float* W2   = (const float*)d_in[7];
  const float* b2   = (const float*)d_in[8];
  const float* We   = (const float*)d_in[9];
  const float* be   = (const float*)d_in[10];
  const float* Wout = (const float*)d_in[11];
  const float* bout = (const float*)d_in[12];
  float* out = (float*)d_out;

  const int N = in_sizes[0] / DN;
  const int maxt = (N + TILE - 1) / TILE + PAIRS;

  char* ws = (char*)d_ws;
  size_t off = 0;
  auto take = [&](size_t bytes) -> char* {
    char* p = ws + off;
    off += (bytes + 255) & ~(size_t)255;
    return p;
  };
  int* cnt = (int*)take(PAIRS * 4);
  int* c2  = (int*)take(PAIRS * 4);
  int* ntl = (int*)take(4);
  int* seg = (int*)take((PAIRS + 1) * 4);
  int* tp  = (int*)take((size_t)maxt * 4);
  int* tst = (int*)take((size_t)maxt * 4);
  int* tnr = (int*)take((size_t)maxt * 4);
  int* ridx = (int*)take((size_t)N * 4);
  unsigned short* W1t = (unsigned short*)take((size_t)J_TYPES * 65536 * 2);
  unsigned short* W2t = (unsigned short*)take((size_t)J_TYPES * 65536 * 2);
  unsigned short* Wet = (unsigned short*)take((size_t)DE * DO * 2);
  unsigned short* Ut  = (unsigned short*)take((size_t)3 * 65536 * 2);
  (void)ws_size; (void)n_in; (void)out_size;

  hipMemsetAsync(cnt, 0, (size_t)((char*)seg - (char*)cnt), stream);
  prep_w_k<<<1024, 256, 0, stream>>>(W1, W2, We, Wout, W1t, W2t, Wet, Ut);
  hist_k<<<400, 256, 0, stream>>>(ty1, ty2, cnt, N);
  scan_tiles_k<<<1, 512, 0, stream>>>(cnt, seg, tp, tst, tnr, ntl);
  scatter_k<<<256, 256, 0, stream>>>(ty1, ty2, seg, c2, ridx, N);
  fused_k<<<maxt, 512, 0, stream>>>(n1, n2, eg, W1t, W2t, Wet, Ut, b1, b2, be, bout,
                                    ridx, tp, tst, tnr, ntl, out);
}